// Round 11
// baseline (185.014 us; speedup 1.0000x reference)
//
#include <hip/hip_runtime.h>
#include <hip/hip_fp16.h>
#include <math.h>

#define HH 512
#define WW 512
#define BB 4
#define NPIX (BB * HH * WW)

#define HS 2                 // core rows per wave (slot algebra is rotation-safe)
#define NSX 9                // strips: 9 x 60 core cols >= 512
#define NBAND (HH / HS)      // 256
#define NWAVES (NSX * NBAND * BB)   // 9216
#define NBLK (NWAVES / 4)           // 2304

constexpr float TAUf   = 0.01f;
constexpr float RHOf   = 1.99f;
constexpr float SIGMAf = (float)(1.0 / 0.01 / 72.0);
constexpr float INV1PT = (float)(1.0 / 1.01);

__device__ __forceinline__ float SD(float v) { return __shfl_down(v, 1, 64); }  // lane+1
__device__ __forceinline__ float SUp(float v) { return __shfl_up(v, 1, 64); }   // lane-1

// Fused state record F (uint2): .x = half2(x2, r0), .y = half2(r1, y_half)
// y_half bits pass through unchanged every iteration (no re-rounding drift).

// MODE: 0 = iter 0 (analytic x=y,r=0,u=0); 1 = mid iter; 2 = last iter (x-only, f32 out)
template <int MODE>
__global__ __launch_bounds__(256) void sweep(
    const float* __restrict__ y, const int* __restrict__ ths_p,
    const uint2* __restrict__ f_in, const uint2* __restrict__ u_in,
    uint2* __restrict__ f_out, uint2* __restrict__ u_out,
    float* __restrict__ xout)
{
    const int tid  = threadIdx.x;
    const int lane = tid & 63;
    const int wid  = blockIdx.x * 4 + (tid >> 6);
    const int sx   = wid % NSX;
    const int t2   = wid / NSX;
    const int band = t2 & (NBAND - 1);
    const int b    = t2 / NBAND;
    const int R0   = band * HS;
    const int w    = sx * 60 - 2 + lane;
    const int boff = b * (HH * WW);
    const bool wok = ((unsigned)w) < (unsigned)WW;
    const float mA = (w >= 1 && w < WW) ? 1.f : 0.f;
    const float mB = (w >= 0 && w < WW - 1) ? 1.f : 0.f;
    const bool cok = (lane >= 2) && (lane < 62) && (w < WW);

    const float ths  = (float)ths_p[0];
    const float tl1_ = TAUf * (ths * 0.1f);   // rinv = min(tl1_*rsq(d), 1)
    const float l2_  = ths * 0.15f;           // ui   = min(l2_ *rsq(d), 1)

    // register rings (slot labels are RELATIVE: producer/consumer share (k+c)&3
    // formulas, so any R0 parity works — no R0%4 requirement)
    float uf0[4], uf1[4], uf2[4], uf3[4];     // u rows (unpacked f32)
    float i0r[2], i1r[2];                     // eps2_adj rows
    float sr[2];                              // s rows
    float t1r[2];                             // t1 rows
    float v0r[4];                             // v0(row)
    float v1r[2];                             // v1(row)
    #pragma unroll
    for (int q = 0; q < 4; ++q) { uf0[q]=uf1[q]=uf2[q]=uf3[q]=0.f; v0r[q]=0.f; }
    i0r[0]=i0r[1]=i1r[0]=i1r[1]=0.f;
    sr[0]=sr[1]=0.f; t1r[0]=t1r[1]=0.f; v1r[0]=v1r[1]=0.f;

    auto uload = [&](int row) -> uint2 {
        uint2 z; z.x = 0u; z.y = 0u;
        if (((unsigned)row) < (unsigned)HH && wok)
            z = u_in[(size_t)(boff + row * WW + w)];
        return z;
    };
    auto fload = [&](int row) -> uint2 {
        uint2 z; z.x = 0u; z.y = 0u;
        if (((unsigned)row) < (unsigned)HH && wok)
            z = f_in[(size_t)(boff + row * WW + w)];
        return z;
    };
    auto unpk = [&](int slot, uint2 raw) {
        __half2 lo = *(reinterpret_cast<__half2*>(&raw.x));
        __half2 hi = *(reinterpret_cast<__half2*>(&raw.y));
        uf0[slot] = __low2float(lo); uf1[slot] = __high2float(lo);
        uf2[slot] = __low2float(hi); uf3[slot] = __high2float(hi);
    };
    auto compI = [&](int rr, int islot, int c, int d, int uu_) {
        if (((unsigned)rr) < (unsigned)HH) {
            float hD  = (rr < HH - 1) ? 1.f : 0.f;
            float u1c = uf1[c], u2c = uf2[c];
            i0r[islot] = uf0[c] - uf0[d] - SD(u1c) + mA * u1c;
            i1r[islot] = u2c - SD(u2c) - hD * uf3[c] + uf3[uu_];
        } else { i0r[islot] = 0.f; i1r[islot] = 0.f; }
    };

    if (MODE == 2) {
        // ---- last iter: only x output (f32), 2-deep prefetch ----
        unpk(2, uload(R0 - 2));
        unpk(3, uload(R0 - 1));
        unpk(0, uload(R0));
        compI(R0 - 1, 1, 3, 0, 2);
        uint2 puA = uload(R0 + 1);
        uint2 puB = uload(R0 + 2);
        uint2 pfA = fload(R0);
        uint2 pfB = fload(R0 + 1);
        #pragma unroll
        for (int k = 0; k < HS; ++k) {
            const int rr = R0 + k;
            unpk((k + 1) & 3, puA);
            puA = puB;
            if (k < HS - 2) puB = uload(R0 + k + 3);
            __half2 lo = *(reinterpret_cast<__half2*>(&pfA.x));
            __half2 hi = *(reinterpret_cast<__half2*>(&pfA.y));
            float x2v = __low2float(lo);
            float yv  = __high2float(hi);
            pfA = pfB;
            if (k < HS - 2) pfB = fload(R0 + k + 2);
            compI(rr, k & 1, k & 3, (k + 1) & 3, (k + 3) & 3);
            float hD = (rr < HH - 1) ? 1.f : 0.f;
            float i0c = i0r[k & 1], i1c = i1r[k & 1], i1u = i1r[(k + 1) & 1];
            float i0l = SUp(i0c);
            float na = TAUf * (mA * i0l - mB * i0c + i1u - hD * i1c);
            float x = (x2v - na + TAUf * yv) * INV1PT;
            if (cok) xout[boff + rr * WW + w] = x2v + RHOf * (x - x2v);
        }
        return;
    }

    // s,t(rr); relax writes on core rows; returns s, t0, t1 for this row
    auto compS = [&](int rr, int isc, int isp,
                     float yv, float x2v, float r20v, float r21v, unsigned yraw,
                     bool coreRow, float &sOut, float &t0Out, float &t1Out) {
        if (((unsigned)rr) < (unsigned)HH) {
            if (MODE == 0) {
                sOut = yv; t0Out = 0.f; t1Out = 0.f;
                if (coreRow && cok) {
                    int idx = boff + rr * WW + w;
                    unsigned hb = (unsigned)__half_as_ushort(__float2half(yv));
                    uint2 st; st.x = hb; st.y = hb << 16;   // {x2=y, r0=0, r1=0, y}
                    f_out[(size_t)idx] = st;
                }
            } else {
                float hD = (rr < HH - 1) ? 1.f : 0.f;
                float i0c = i0r[isc], i1c = i1r[isc], i1u = i1r[isp];
                float i0l = SUp(i0c);
                float na = TAUf * (mA * i0l - mB * i0c + i1u - hD * i1c);
                float x = (x2v - na + TAUf * yv) * INV1PT;
                float rr0 = r20v + TAUf * i0c;
                float rr1 = r21v + TAUf * i1c;
                float d = rr0 * rr0 + rr1 * rr1;
                float rinv = fminf(tl1_ * __builtin_amdgcn_rsqf(d), 1.0f);
                float r0 = rr0 - rr0 * rinv;
                float r1 = rr1 - rr1 * rinv;
                sOut  = 2.f * x  - x2v;
                t0Out = 2.f * r0 - r20v;
                t1Out = 2.f * r1 - r21v;
                if (coreRow && cok) {
                    int idx = boff + rr * WW + w;
                    __half2 lo2 = __floats2half2_rn(x2v + RHOf * (x - x2v),
                                                    r20v + RHOf * (r0 - r20v));
                    unsigned r1b = (unsigned)__half_as_ushort(
                        __float2half(r21v + RHOf * (r1 - r21v)));
                    uint2 st; st.x = *(unsigned*)&lo2; st.y = r1b | (yraw << 16);
                    f_out[(size_t)idx] = st;
                }
            }
        } else { sOut = 0.f; t0Out = 0.f; t1Out = 0.f; }
    };

    auto compU = [&](int ro, int v0c_s, int v0u_s, int v1c_s, int v1d_s, int uslot) {
        float hD  = (ro < HH - 1) ? 1.f : 0.f;
        float v0c = v0r[v0c_s], v0u = v0r[v0u_s];
        float v1c = v1r[v1c_s], v1d = v1r[v1d_s];
        float v0l = SUp(v0c);
        float v1l = SUp(v1c);
        float G0 = v0c - v0u;
        float G1 = mA * (v0c - v0l);
        float G2 = v1c - mA * v1l;
        float G3 = hD * (v1d - v1c);
        float u0v, u1v, u2v, u3v;
        if (MODE == 0) { u0v = u1v = u2v = u3v = 0.f; }
        else { u0v = uf0[uslot]; u1v = uf1[uslot]; u2v = uf2[uslot]; u3v = uf3[uslot]; }
        float uu0 = u0v + SIGMAf * G0;
        float uu1 = u1v + SIGMAf * G1;
        float uu2 = u2v + SIGMAf * G2;
        float uu3 = u3v + SIGMAf * G3;
        float d = uu0 * uu0 + uu1 * uu1 + uu2 * uu2 + uu3 * uu3;
        float ui = fminf(l2_ * __builtin_amdgcn_rsqf(d), 1.0f);
        if (cok) {
            int idx = boff + ro * WW + w;
            __half2 lo = __floats2half2_rn(u0v + RHOf * (uu0 * ui - u0v),
                                           u1v + RHOf * (uu1 * ui - u1v));
            __half2 hi = __floats2half2_rn(u2v + RHOf * (uu2 * ui - u2v),
                                           u3v + RHOf * (uu3 * ui - u3v));
            uint2 st; st.x = *(unsigned*)&lo; st.y = *(unsigned*)&hi;
            u_out[(size_t)idx] = st;
        }
    };

    // ---- prologue (2-deep prefetch) ----
    uint2 puA, puB, pfA, pfB;
    puA.x = puA.y = puB.x = puB.y = 0u;
    pfA.x = pfA.y = pfB.x = pfB.y = 0u;
    float pyA = 0.f, pyB = 0.f;
    if (MODE != 0) {
        unpk(1, uload(R0 - 3));
        unpk(2, uload(R0 - 2));
        unpk(3, uload(R0 - 1));
        compI(R0 - 2, 0, 2, 3, 1);
        puA = uload(R0);          // unpack at k=0
        puB = uload(R0 + 1);      // unpack at k=1
        pfA = fload(R0 - 1);      // consume at k=0
        pfB = fload(R0);          // consume at k=1
    } else {
        int rowA = R0 - 1; bool okA = (((unsigned)rowA) < (unsigned)HH) && wok;
        pyA = okA ? y[boff + rowA * WW + w] : 0.f;
        pyB = wok ? y[boff + R0 * WW + w] : 0.f;   // row R0 always in range
    }

    // ---- main pipeline: rr = R0-1 .. R0+HS+1 ----
    #pragma unroll
    for (int k = 0; k < HS + 3; ++k) {
        const int rr = R0 - 1 + k;

        float yv, x2v = 0.f, r20v = 0.f, r21v = 0.f; unsigned yraw = 0u;
        if (MODE != 0) {
            unpk(k & 3, puA);               // u row R0+k (loaded at stage k-2)
            puA = puB;
            if (k <= HS) puB = uload(R0 + k + 2);
            __half2 lo = *(reinterpret_cast<__half2*>(&pfA.x));
            __half2 hi = *(reinterpret_cast<__half2*>(&pfA.y));
            x2v  = __low2float(lo);  r20v = __high2float(lo);
            r21v = __low2float(hi);  yv   = __high2float(hi);
            yraw = pfA.y >> 16;
            pfA = pfB;
            if (k <= HS) pfB = fload(R0 + k + 1);
        } else {
            yv = pyA;
            pyA = pyB;
            if (k <= HS) {
                int row = R0 + k + 1;
                bool ok = (((unsigned)row) < (unsigned)HH) && wok;
                pyB = ok ? y[boff + row * WW + w] : 0.f;
            }
        }
        if (MODE != 0) compI(rr, (k + 1) & 1, (k + 3) & 3, k & 3, (k + 2) & 3);

        float sN, t0N, t1N;
        compS(rr, (k + 1) & 1, k & 1, yv, x2v, r20v, r21v, yraw,
              (k >= 1 && k <= HS), sN, t0N, t1N);

        // v-ring updates for row rr (v0) and row rr-1 (v1)
        {
            float sPrev  = sr[k & 1];
            float t1Prev = t1r[k & 1];
            float hDm1   = (rr < HH) ? 1.f : 0.f;
            v0r[(k + 3) & 3] = mB * (SD(sN) - sN) - t0N;
            v1r[k & 1]       = hDm1 * (sN - sPrev) - t1Prev;
            sr[(k + 1) & 1]  = sN;
            t1r[(k + 1) & 1] = t1N;
        }

        if (k >= 3) compU(R0 - 3 + k, (k + 1) & 3, k & 3, (k + 1) & 1, k & 1,
                          (k + 1) & 3);
    }
}

extern "C" void kernel_launch(void* const* d_in, const int* in_sizes, int n_in,
                              void* d_out, int out_size, void* d_ws, size_t ws_size,
                              hipStream_t stream)
{
    const float* y   = (const float*)d_in[0];
    const int*   ths = (const int*)d_in[1];
    uint2* ws2 = (uint2*)d_ws;

    uint2* FA = ws2;
    uint2* UA = ws2 + (size_t)NPIX;
    uint2* FB = ws2 + 2 * (size_t)NPIX;
    uint2* UB = ws2 + 3 * (size_t)NPIX;
    float* xout = (float*)d_out;

    dim3 block(256);
    dim3 grid(NBLK);

    // iter 0 (analytic) -> B
    sweep<0><<<grid, block, 0, stream>>>(y, ths, nullptr, nullptr, FB, UB, nullptr);
    // iters 1..8 alternate
    uint2 *fi = FB, *ui = UB, *fo = FA, *uo = UA;
    for (int it = 1; it <= 8; ++it) {
        sweep<1><<<grid, block, 0, stream>>>(y, ths, fi, ui, fo, uo, nullptr);
        uint2* t;
        t = fi; fi = fo; fo = t;
        t = ui; ui = uo; uo = t;
    }
    // iter 9: x only -> d_out
    sweep<2><<<grid, block, 0, stream>>>(y, ths, fi, ui, nullptr, nullptr, xout);
}

// Round 13
// 168.465 us; speedup vs baseline: 1.0982x; 1.0982x over previous
//
#include <hip/hip_runtime.h>
#include <hip/hip_fp16.h>
#include <math.h>

#define HH 512
#define WW 512
#define BB 4
#define NPIX (BB * HH * WW)

#define HS 4                 // core rows per wave (optimum: {2,4,8}->{185,160,211})
#define NSX 9                // strips: 9 x 60 core cols >= 512
#define NBAND (HH / HS)      // 128
#define NWAVES (NSX * NBAND * BB)   // 4608
#define NBLK (NWAVES / 4)           // 1152

constexpr float TAUf   = 0.01f;
constexpr float RHOf   = 1.99f;
constexpr float SIGMAf = (float)(1.0 / 0.01 / 72.0);
constexpr float INV1PT = (float)(1.0 / 1.01);

__device__ __forceinline__ float SD(float v) { return __shfl_down(v, 1, 64); }    // lane+1
__device__ __forceinline__ unsigned SDu(unsigned v) { return __shfl_down(v, 1, 64); }
__device__ __forceinline__ float SUp(float v) { return __shfl_up(v, 1, 64); }     // lane-1

// Fused state record F (uint2): .x = half2(x2, r0), .y = half2(r1, y_half)
// u record (uint2): .x = half2(u0, u1), .y = half2(u2, u3)
// y_half bits pass through unchanged every iteration (no re-rounding drift).

// MODE: 0 = iter 0 (analytic x=y,r=0,u=0); 1 = mid iter; 2 = last iter (x-only, f32 out)
template <int MODE>
__global__ __launch_bounds__(256) void sweep(
    const float* __restrict__ y, const int* __restrict__ ths_p,
    const uint2* __restrict__ f_in, const uint2* __restrict__ u_in,
    uint2* __restrict__ f_out, uint2* __restrict__ u_out,
    float* __restrict__ xout)
{
    const int tid  = threadIdx.x;
    const int lane = tid & 63;
    const int wid  = blockIdx.x * 4 + (tid >> 6);
    const int sx   = wid % NSX;
    const int t2   = wid / NSX;
    const int band = t2 & (NBAND - 1);
    const int b    = t2 / NBAND;
    const int R0   = band * HS;
    const int w    = sx * 60 - 2 + lane;
    const int boff = b * (HH * WW);
    const bool wok = ((unsigned)w) < (unsigned)WW;
    const float mA = (w >= 1 && w < WW) ? 1.f : 0.f;
    const float mB = (w >= 0 && w < WW - 1) ? 1.f : 0.f;
    const bool cok = (lane >= 2) && (lane < 62) && (w < WW);

    const float ths  = (float)ths_p[0];
    const float tl1_ = TAUf * (ths * 0.1f);   // rinv = min(tl1_*rsq(d), 1)
    const float l2_  = ths * 0.15f;           // ui   = min(l2_ *rsq(d), 1)

    // register rings
    float uf0[4], uf1[4], uf2[4], uf3[4];     // u rows (unpacked f32)
    unsigned u12r[4];                         // packed (u1,u2) raw halves per row
    float i0r[2], i1r[2];                     // eps2_adj rows
    float sr[2];                              // s rows
    float t1r[2];                             // t1 rows
    float v0r[4];                             // v0(row)
    float v1r[2];                             // v1(row)
    #pragma unroll
    for (int q = 0; q < 4; ++q) { uf0[q]=uf1[q]=uf2[q]=uf3[q]=0.f; v0r[q]=0.f; u12r[q]=0u; }
    i0r[0]=i0r[1]=i1r[0]=i1r[1]=0.f;
    sr[0]=sr[1]=0.f; t1r[0]=t1r[1]=0.f; v1r[0]=v1r[1]=0.f;

    auto uload = [&](int row) -> uint2 {
        uint2 z; z.x = 0u; z.y = 0u;
        if (((unsigned)row) < (unsigned)HH && wok)
            z = u_in[(size_t)(boff + row * WW + w)];
        return z;
    };
    auto fload = [&](int row) -> uint2 {
        uint2 z; z.x = 0u; z.y = 0u;
        if (((unsigned)row) < (unsigned)HH && wok)
            z = f_in[(size_t)(boff + row * WW + w)];
        return z;
    };
    auto unpk = [&](int slot, uint2 raw) {
        __half2 lo = *(reinterpret_cast<__half2*>(&raw.x));
        __half2 hi = *(reinterpret_cast<__half2*>(&raw.y));
        uf0[slot] = __low2float(lo); uf1[slot] = __high2float(lo);
        uf2[slot] = __low2float(hi); uf3[slot] = __high2float(hi);
        u12r[slot] = (raw.x >> 16) | (raw.y << 16);   // (u1, u2) packed
    };
    // i(rr): one packed shuffle for (u1,u2)(w+1); bit-exact vs two float shuffles
    auto compI = [&](int rr, int islot, int c, int d, int uu_) {
        if (((unsigned)rr) < (unsigned)HH) {
            float hD  = (rr < HH - 1) ? 1.f : 0.f;
            unsigned pp = SDu(u12r[c]);
            __half2 ph = *(reinterpret_cast<__half2*>(&pp));
            float u1n = __low2float(ph);    // u1(w+1)
            float u2n = __high2float(ph);   // u2(w+1)
            i0r[islot] = uf0[c] - uf0[d] - u1n + mA * uf1[c];
            i1r[islot] = uf2[c] - u2n - hD * uf3[c] + uf3[uu_];
        } else { i0r[islot] = 0.f; i1r[islot] = 0.f; }
    };

    if (MODE == 2) {
        // ---- last iter: only x output (f32), 3-deep prefetch ----
        unpk(2, uload(R0 - 2));
        unpk(3, uload(R0 - 1));
        unpk(0, uload(R0));
        compI(R0 - 1, 1, 3, 0, 2);
        uint2 puA = uload(R0 + 1);
        uint2 puB = uload(R0 + 2);
        uint2 puC = uload(R0 + 3);
        uint2 pfA = fload(R0);
        uint2 pfB = fload(R0 + 1);
        uint2 pfC = fload(R0 + 2);
        #pragma unroll
        for (int k = 0; k < HS; ++k) {
            const int rr = R0 + k;
            unpk((k + 1) & 3, puA);
            puA = puB; puB = puC;
            if (k <= HS - 4) puC = uload(R0 + k + 4);
            __half2 lo = *(reinterpret_cast<__half2*>(&pfA.x));
            __half2 hi = *(reinterpret_cast<__half2*>(&pfA.y));
            float x2v = __low2float(lo);
            float yv  = __high2float(hi);
            pfA = pfB; pfB = pfC;
            if (k <= HS - 4) pfC = fload(R0 + k + 3);
            compI(rr, k & 1, k & 3, (k + 1) & 3, (k + 3) & 3);
            float hD = (rr < HH - 1) ? 1.f : 0.f;
            float i0c = i0r[k & 1], i1c = i1r[k & 1], i1u = i1r[(k + 1) & 1];
            float i0l = SUp(i0c);
            float na = TAUf * (mA * i0l - mB * i0c + i1u - hD * i1c);
            float x = (x2v - na + TAUf * yv) * INV1PT;
            if (cok) xout[boff + rr * WW + w] = x2v + RHOf * (x - x2v);
        }
        return;
    }

    // s,t(rr); relax writes on core rows; returns s, t0, t1 for this row
    auto compS = [&](int rr, int isc, int isp,
                     float yv, float x2v, float r20v, float r21v, unsigned yraw,
                     bool coreRow, float &sOut, float &t0Out, float &t1Out) {
        if (((unsigned)rr) < (unsigned)HH) {
            if (MODE == 0) {
                sOut = yv; t0Out = 0.f; t1Out = 0.f;
                if (coreRow && cok) {
                    int idx = boff + rr * WW + w;
                    unsigned hb = (unsigned)__half_as_ushort(__float2half(yv));
                    uint2 st; st.x = hb; st.y = hb << 16;   // {x2=y, r0=0, r1=0, y}
                    f_out[(size_t)idx] = st;
                }
            } else {
                float hD = (rr < HH - 1) ? 1.f : 0.f;
                float i0c = i0r[isc], i1c = i1r[isc], i1u = i1r[isp];
                float i0l = SUp(i0c);
                float na = TAUf * (mA * i0l - mB * i0c + i1u - hD * i1c);
                float x = (x2v - na + TAUf * yv) * INV1PT;
                float rr0 = r20v + TAUf * i0c;
                float rr1 = r21v + TAUf * i1c;
                float d = rr0 * rr0 + rr1 * rr1;
                float rinv = fminf(tl1_ * __builtin_amdgcn_rsqf(d), 1.0f);
                float r0 = rr0 - rr0 * rinv;
                float r1 = rr1 - rr1 * rinv;
                sOut  = 2.f * x  - x2v;
                t0Out = 2.f * r0 - r20v;
                t1Out = 2.f * r1 - r21v;
                if (coreRow && cok) {
                    int idx = boff + rr * WW + w;
                    __half2 lo2 = __floats2half2_rn(x2v + RHOf * (x - x2v),
                                                    r20v + RHOf * (r0 - r20v));
                    unsigned r1b = (unsigned)__half_as_ushort(
                        __float2half(r21v + RHOf * (r1 - r21v)));
                    uint2 st; st.x = *(unsigned*)&lo2; st.y = r1b | (yraw << 16);
                    f_out[(size_t)idx] = st;
                }
            }
        } else { sOut = 0.f; t0Out = 0.f; t1Out = 0.f; }
    };

    auto compU = [&](int ro, int v0c_s, int v0u_s, int v1c_s, int v1d_s, int uslot) {
        float hD  = (ro < HH - 1) ? 1.f : 0.f;
        float v0c = v0r[v0c_s], v0u = v0r[v0u_s];
        float v1c = v1r[v1c_s], v1d = v1r[v1d_s];
        float v0l = SUp(v0c);
        float v1l = SUp(v1c);
        float G0 = v0c - v0u;
        float G1 = mA * (v0c - v0l);
        float G2 = v1c - mA * v1l;
        float G3 = hD * (v1d - v1c);
        float u0v, u1v, u2v, u3v;
        if (MODE == 0) { u0v = u1v = u2v = u3v = 0.f; }
        else { u0v = uf0[uslot]; u1v = uf1[uslot]; u2v = uf2[uslot]; u3v = uf3[uslot]; }
        float uu0 = u0v + SIGMAf * G0;
        float uu1 = u1v + SIGMAf * G1;
        float uu2 = u2v + SIGMAf * G2;
        float uu3 = u3v + SIGMAf * G3;
        float d = uu0 * uu0 + uu1 * uu1 + uu2 * uu2 + uu3 * uu3;
        float ui = fminf(l2_ * __builtin_amdgcn_rsqf(d), 1.0f);
        if (cok) {
            int idx = boff + ro * WW + w;
            __half2 lo = __floats2half2_rn(u0v + RHOf * (uu0 * ui - u0v),
                                           u1v + RHOf * (uu1 * ui - u1v));
            __half2 hi = __floats2half2_rn(u2v + RHOf * (uu2 * ui - u2v),
                                           u3v + RHOf * (uu3 * ui - u3v));
            uint2 st; st.x = *(unsigned*)&lo; st.y = *(unsigned*)&hi;
            u_out[(size_t)idx] = st;
        }
    };

    // ---- prologue (3-deep prefetch) ----
    uint2 puA, puB, puC, pfA, pfB, pfC;
    puA.x = puA.y = puB.x = puB.y = puC.x = puC.y = 0u;
    pfA.x = pfA.y = pfB.x = pfB.y = pfC.x = pfC.y = 0u;
    float pyA = 0.f, pyB = 0.f;
    if (MODE != 0) {
        unpk(1, uload(R0 - 3));
        unpk(2, uload(R0 - 2));
        unpk(3, uload(R0 - 1));
        compI(R0 - 2, 0, 2, 3, 1);
        puA = uload(R0);          // consume at k=0
        puB = uload(R0 + 1);      // k=1
        puC = uload(R0 + 2);      // k=2
        pfA = fload(R0 - 1);      // consume at k=0
        pfB = fload(R0);          // k=1
        pfC = fload(R0 + 1);      // k=2
    } else {
        int rowA = R0 - 1; bool okA = (((unsigned)rowA) < (unsigned)HH) && wok;
        pyA = okA ? y[boff + rowA * WW + w] : 0.f;
        pyB = wok ? y[boff + R0 * WW + w] : 0.f;   // row R0 always in range
    }

    // ---- main pipeline: rr = R0-1 .. R0+HS+1 ----
    #pragma unroll
    for (int k = 0; k < HS + 3; ++k) {
        const int rr = R0 - 1 + k;

        float yv, x2v = 0.f, r20v = 0.f, r21v = 0.f; unsigned yraw = 0u;
        if (MODE != 0) {
            unpk(k & 3, puA);               // u row R0+k (loaded 3 stages earlier)
            puA = puB; puB = puC;
            if (k <= HS - 1) puC = uload(R0 + k + 3);   // rows R0+3 .. R0+HS+2
            __half2 lo = *(reinterpret_cast<__half2*>(&pfA.x));
            __half2 hi = *(reinterpret_cast<__half2*>(&pfA.y));
            x2v  = __low2float(lo);  r20v = __high2float(lo);
            r21v = __low2float(hi);  yv   = __high2float(hi);
            yraw = pfA.y >> 16;
            pfA = pfB; pfB = pfC;
            if (k <= HS - 1) pfC = fload(R0 + k + 2);   // rows R0+2 .. R0+HS+1
        } else {
            yv = pyA;
            pyA = pyB;
            if (k <= HS) {
                int row = R0 + k + 1;
                bool ok = (((unsigned)row) < (unsigned)HH) && wok;
                pyB = ok ? y[boff + row * WW + w] : 0.f;
            }
        }
        if (MODE != 0) compI(rr, (k + 1) & 1, (k + 3) & 3, k & 3, (k + 2) & 3);

        float sN, t0N, t1N;
        compS(rr, (k + 1) & 1, k & 1, yv, x2v, r20v, r21v, yraw,
              (k >= 1 && k <= HS), sN, t0N, t1N);

        // v-ring updates for row rr (v0) and row rr-1 (v1)
        {
            float sPrev  = sr[k & 1];
            float t1Prev = t1r[k & 1];
            float hDm1   = (rr < HH) ? 1.f : 0.f;
            v0r[(k + 3) & 3] = mB * (SD(sN) - sN) - t0N;
            v1r[k & 1]       = hDm1 * (sN - sPrev) - t1Prev;
            sr[(k + 1) & 1]  = sN;
            t1r[(k + 1) & 1] = t1N;
        }

        if (k >= 3) compU(R0 - 3 + k, (k + 1) & 3, k & 3, (k + 1) & 1, k & 1,
                          (k + 1) & 3);
    }
}

extern "C" void kernel_launch(void* const* d_in, const int* in_sizes, int n_in,
                              void* d_out, int out_size, void* d_ws, size_t ws_size,
                              hipStream_t stream)
{
    const float* y   = (const float*)d_in[0];
    const int*   ths = (const int*)d_in[1];
    uint2* ws2 = (uint2*)d_ws;

    uint2* FA = ws2;
    uint2* UA = ws2 + (size_t)NPIX;
    uint2* FB = ws2 + 2 * (size_t)NPIX;
    uint2* UB = ws2 + 3 * (size_t)NPIX;
    float* xout = (float*)d_out;

    dim3 block(256);
    dim3 grid(NBLK);

    // iter 0 (analytic) -> B
    sweep<0><<<grid, block, 0, stream>>>(y, ths, nullptr, nullptr, FB, UB, nullptr);
    // iters 1..8 alternate
    uint2 *fi = FB, *ui = UB, *fo = FA, *uo = UA;
    for (int it = 1; it <= 8; ++it) {
        sweep<1><<<grid, block, 0, stream>>>(y, ths, fi, ui, fo, uo, nullptr);
        uint2* t;
        t = fi; fi = fo; fo = t;
        t = ui; ui = uo; uo = t;
    }
    // iter 9: x only -> d_out
    sweep<2><<<grid, block, 0, stream>>>(y, ths, fi, ui, nullptr, nullptr, xout);
}

// Round 14
// 161.205 us; speedup vs baseline: 1.1477x; 1.0450x over previous
//
#include <hip/hip_runtime.h>
#include <hip/hip_fp16.h>
#include <math.h>

#define HH 512
#define WW 512
#define BB 4
#define NPIX (BB * HH * WW)

#define HS 4                 // core rows per wave (optimum: {2,4,8}->{185,160,211})
#define NSX 9                // strips: 9 x 60 core cols >= 512
#define NBAND (HH / HS)      // 128
#define NWAVES (NSX * NBAND * BB)   // 4608
#define NBLK (NWAVES / 4)           // 1152

constexpr float TAUf   = 0.01f;
constexpr float RHOf   = 1.99f;
constexpr float SIGMAf = (float)(1.0 / 0.01 / 72.0);
constexpr float INV1PT = (float)(1.0 / 1.01);

__device__ __forceinline__ float SD(float v) { return __shfl_down(v, 1, 64); }    // lane+1
__device__ __forceinline__ unsigned SDu(unsigned v) { return __shfl_down(v, 1, 64); }
__device__ __forceinline__ float SUp(float v) { return __shfl_up(v, 1, 64); }     // lane-1

// Fused state record F (uint2): .x = half2(x2, r0), .y = half2(r1, y_half)
// u record (uint2): .x = half2(u0, u1), .y = half2(u2, u3)
// y_half bits pass through unchanged every iteration (no re-rounding drift).

// MODE: 0 = iter 0 (analytic x=y,r=0,u=0); 1 = mid iter; 2 = last iter (x-only, f32 out)
template <int MODE>
__global__ __launch_bounds__(256) void sweep(
    const float* __restrict__ y, const int* __restrict__ ths_p,
    const uint2* __restrict__ f_in, const uint2* __restrict__ u_in,
    uint2* __restrict__ f_out, uint2* __restrict__ u_out,
    float* __restrict__ xout)
{
    const int tid  = threadIdx.x;
    const int lane = tid & 63;
    const int wid  = blockIdx.x * 4 + (tid >> 6);
    const int sx   = wid % NSX;
    const int t2   = wid / NSX;
    const int band = t2 & (NBAND - 1);
    const int b    = t2 / NBAND;
    const int R0   = band * HS;
    const int w    = sx * 60 - 2 + lane;
    const int boff = b * (HH * WW);
    const bool wok = ((unsigned)w) < (unsigned)WW;
    const float mA = (w >= 1 && w < WW) ? 1.f : 0.f;
    const float mB = (w >= 0 && w < WW - 1) ? 1.f : 0.f;
    const bool cok = (lane >= 2) && (lane < 62) && (w < WW);

    const float ths  = (float)ths_p[0];
    const float tl1_ = TAUf * (ths * 0.1f);   // rinv = min(tl1_*rsq(d), 1)
    const float l2_  = ths * 0.15f;           // ui   = min(l2_ *rsq(d), 1)

    // register rings
    float uf0[4], uf1[4], uf2[4], uf3[4];     // u rows (unpacked f32)
    unsigned u12r[4];                         // packed (u1,u2) raw halves per row
    float i0r[2], i1r[2];                     // eps2_adj rows
    float sr[2];                              // s rows (rr&1)
    float t1r[2];                             // t1 rows (rr&1)
    float v0r[4];                             // v0(row), slot row&3
    float v1r[2];                             // v1(row), slot row&1
    #pragma unroll
    for (int q = 0; q < 4; ++q) { uf0[q]=uf1[q]=uf2[q]=uf3[q]=0.f; v0r[q]=0.f; u12r[q]=0u; }
    i0r[0]=i0r[1]=i1r[0]=i1r[1]=0.f;
    sr[0]=sr[1]=0.f; t1r[0]=t1r[1]=0.f; v1r[0]=v1r[1]=0.f;

    auto uload = [&](int row) -> uint2 {
        uint2 z; z.x = 0u; z.y = 0u;
        if (((unsigned)row) < (unsigned)HH && wok)
            z = u_in[(size_t)(boff + row * WW + w)];
        return z;
    };
    auto fload = [&](int row) -> uint2 {
        uint2 z; z.x = 0u; z.y = 0u;
        if (((unsigned)row) < (unsigned)HH && wok)
            z = f_in[(size_t)(boff + row * WW + w)];
        return z;
    };
    auto unpk = [&](int slot, uint2 raw) {
        __half2 lo = *(reinterpret_cast<__half2*>(&raw.x));
        __half2 hi = *(reinterpret_cast<__half2*>(&raw.y));
        uf0[slot] = __low2float(lo); uf1[slot] = __high2float(lo);
        uf2[slot] = __low2float(hi); uf3[slot] = __high2float(hi);
        u12r[slot] = (raw.x >> 16) | (raw.y << 16);   // (u1, u2) packed
    };
    // i(rr): one packed shuffle for (u1,u2)(w+1); bit-exact vs two float shuffles
    auto compI = [&](int rr, int islot, int c, int d, int uu_) {
        if (((unsigned)rr) < (unsigned)HH) {
            float hD  = (rr < HH - 1) ? 1.f : 0.f;
            unsigned pp = SDu(u12r[c]);
            __half2 ph = *(reinterpret_cast<__half2*>(&pp));
            float u1n = __low2float(ph);    // u1(w+1)
            float u2n = __high2float(ph);   // u2(w+1)
            i0r[islot] = uf0[c] - uf0[d] - u1n + mA * uf1[c];
            i1r[islot] = uf2[c] - u2n - hD * uf3[c] + uf3[uu_];
        } else { i0r[islot] = 0.f; i1r[islot] = 0.f; }
    };

    if (MODE == 2) {
        // ---- last iter: only x output (f32), 2-deep prefetch ----
        unpk(2, uload(R0 - 2));
        unpk(3, uload(R0 - 1));
        unpk(0, uload(R0));
        compI(R0 - 1, 1, 3, 0, 2);
        uint2 puA = uload(R0 + 1);
        uint2 puB = uload(R0 + 2);
        uint2 pfA = fload(R0);
        uint2 pfB = fload(R0 + 1);
        #pragma unroll
        for (int k = 0; k < HS; ++k) {
            const int rr = R0 + k;
            unpk((k + 1) & 3, puA);
            puA = puB;
            if (k < HS - 2) puB = uload(R0 + k + 3);
            __half2 lo = *(reinterpret_cast<__half2*>(&pfA.x));
            __half2 hi = *(reinterpret_cast<__half2*>(&pfA.y));
            float x2v = __low2float(lo);
            float yv  = __high2float(hi);
            pfA = pfB;
            if (k < HS - 2) pfB = fload(R0 + k + 2);
            compI(rr, k & 1, k & 3, (k + 1) & 3, (k + 3) & 3);
            float hD = (rr < HH - 1) ? 1.f : 0.f;
            float i0c = i0r[k & 1], i1c = i1r[k & 1], i1u = i1r[(k + 1) & 1];
            float i0l = SUp(i0c);
            float na = TAUf * (mA * i0l - mB * i0c + i1u - hD * i1c);
            float x = (x2v - na + TAUf * yv) * INV1PT;
            if (cok) xout[boff + rr * WW + w] = x2v + RHOf * (x - x2v);
        }
        return;
    }

    // s,t(rr); relax writes on core rows; returns s, t0, t1 for this row
    auto compS = [&](int rr, int isc, int isp,
                     float yv, float x2v, float r20v, float r21v, unsigned yraw,
                     bool coreRow, float &sOut, float &t0Out, float &t1Out) {
        if (((unsigned)rr) < (unsigned)HH) {
            if (MODE == 0) {
                sOut = yv; t0Out = 0.f; t1Out = 0.f;
                if (coreRow && cok) {
                    int idx = boff + rr * WW + w;
                    unsigned hb = (unsigned)__half_as_ushort(__float2half(yv));
                    uint2 st; st.x = hb; st.y = hb << 16;   // {x2=y, r0=0, r1=0, y}
                    f_out[(size_t)idx] = st;
                }
            } else {
                float hD = (rr < HH - 1) ? 1.f : 0.f;
                float i0c = i0r[isc], i1c = i1r[isc], i1u = i1r[isp];
                float i0l = SUp(i0c);
                float na = TAUf * (mA * i0l - mB * i0c + i1u - hD * i1c);
                float x = (x2v - na + TAUf * yv) * INV1PT;
                float rr0 = r20v + TAUf * i0c;
                float rr1 = r21v + TAUf * i1c;
                float d = rr0 * rr0 + rr1 * rr1;
                float rinv = fminf(tl1_ * __builtin_amdgcn_rsqf(d), 1.0f);
                float r0 = rr0 - rr0 * rinv;
                float r1 = rr1 - rr1 * rinv;
                sOut  = 2.f * x  - x2v;
                t0Out = 2.f * r0 - r20v;
                t1Out = 2.f * r1 - r21v;
                if (coreRow && cok) {
                    int idx = boff + rr * WW + w;
                    __half2 lo2 = __floats2half2_rn(x2v + RHOf * (x - x2v),
                                                    r20v + RHOf * (r0 - r20v));
                    unsigned r1b = (unsigned)__half_as_ushort(
                        __float2half(r21v + RHOf * (r1 - r21v)));
                    uint2 st; st.x = *(unsigned*)&lo2; st.y = r1b | (yraw << 16);
                    f_out[(size_t)idx] = st;
                }
            }
        } else { sOut = 0.f; t0Out = 0.f; t1Out = 0.f; }
    };

    auto compU = [&](int ro, int v0c_s, int v0u_s, int v1c_s, int v1d_s, int uslot) {
        float hD  = (ro < HH - 1) ? 1.f : 0.f;
        float v0c = v0r[v0c_s], v0u = v0r[v0u_s];
        float v1c = v1r[v1c_s], v1d = v1r[v1d_s];
        float v0l = SUp(v0c);
        float v1l = SUp(v1c);
        float G0 = v0c - v0u;
        float G1 = mA * (v0c - v0l);
        float G2 = v1c - mA * v1l;
        float G3 = hD * (v1d - v1c);
        float u0v, u1v, u2v, u3v;
        if (MODE == 0) { u0v = u1v = u2v = u3v = 0.f; }
        else { u0v = uf0[uslot]; u1v = uf1[uslot]; u2v = uf2[uslot]; u3v = uf3[uslot]; }
        float uu0 = u0v + SIGMAf * G0;
        float uu1 = u1v + SIGMAf * G1;
        float uu2 = u2v + SIGMAf * G2;
        float uu3 = u3v + SIGMAf * G3;
        float d = uu0 * uu0 + uu1 * uu1 + uu2 * uu2 + uu3 * uu3;
        float ui = fminf(l2_ * __builtin_amdgcn_rsqf(d), 1.0f);
        if (cok) {
            int idx = boff + ro * WW + w;
            __half2 lo = __floats2half2_rn(u0v + RHOf * (uu0 * ui - u0v),
                                           u1v + RHOf * (uu1 * ui - u1v));
            __half2 hi = __floats2half2_rn(u2v + RHOf * (uu2 * ui - u2v),
                                           u3v + RHOf * (uu3 * ui - u3v));
            uint2 st; st.x = *(unsigned*)&lo; st.y = *(unsigned*)&hi;
            u_out[(size_t)idx] = st;
        }
    };

    // ---- prologue (2-deep prefetch) ----
    uint2 puA, puB, pfA, pfB;
    puA.x = puA.y = puB.x = puB.y = 0u;
    pfA.x = pfA.y = pfB.x = pfB.y = 0u;
    float pyA = 0.f, pyB = 0.f;
    if (MODE != 0) {
        unpk(1, uload(R0 - 3));
        unpk(2, uload(R0 - 2));
        unpk(3, uload(R0 - 1));
        compI(R0 - 2, 0, 2, 3, 1);
        puA = uload(R0);          // unpack at k=0
        puB = uload(R0 + 1);      // unpack at k=1
        pfA = fload(R0 - 1);      // consume at k=0
        pfB = fload(R0);          // consume at k=1
    } else {
        int rowA = R0 - 1; bool okA = (((unsigned)rowA) < (unsigned)HH) && wok;
        pyA = okA ? y[boff + rowA * WW + w] : 0.f;
        pyB = wok ? y[boff + R0 * WW + w] : 0.f;   // row R0 always in range
    }

    // ---- main pipeline: rr = R0-1 .. R0+HS+1 ----
    #pragma unroll
    for (int k = 0; k < HS + 3; ++k) {
        const int rr = R0 - 1 + k;

        float yv, x2v = 0.f, r20v = 0.f, r21v = 0.f; unsigned yraw = 0u;
        if (MODE != 0) {
            unpk(k & 3, puA);               // u row R0+k (loaded at stage k-2)
            puA = puB;
            if (k <= HS) puB = uload(R0 + k + 2);
            __half2 lo = *(reinterpret_cast<__half2*>(&pfA.x));
            __half2 hi = *(reinterpret_cast<__half2*>(&pfA.y));
            x2v  = __low2float(lo);  r20v = __high2float(lo);
            r21v = __low2float(hi);  yv   = __high2float(hi);
            yraw = pfA.y >> 16;
            pfA = pfB;
            if (k <= HS) pfB = fload(R0 + k + 1);
        } else {
            yv = pyA;
            pyA = pyB;
            if (k <= HS) {
                int row = R0 + k + 1;
                bool ok = (((unsigned)row) < (unsigned)HH) && wok;
                pyB = ok ? y[boff + row * WW + w] : 0.f;
            }
        }
        if (MODE != 0) compI(rr, (k + 1) & 1, (k + 3) & 3, k & 3, (k + 2) & 3);

        float sN, t0N, t1N;
        compS(rr, (k + 1) & 1, k & 1, yv, x2v, r20v, r21v, yraw,
              (k >= 1 && k <= HS), sN, t0N, t1N);

        // v-ring updates for row rr (v0) and row rr-1 (v1)
        {
            float sPrev  = sr[k & 1];
            float t1Prev = t1r[k & 1];
            float hDm1   = (rr < HH) ? 1.f : 0.f;
            v0r[(k + 3) & 3] = mB * (SD(sN) - sN) - t0N;
            v1r[k & 1]       = hDm1 * (sN - sPrev) - t1Prev;
            sr[(k + 1) & 1]  = sN;
            t1r[(k + 1) & 1] = t1N;
        }

        if (k >= 3) compU(R0 - 3 + k, (k + 1) & 3, k & 3, (k + 1) & 1, k & 1,
                          (k + 1) & 3);
    }
}

extern "C" void kernel_launch(void* const* d_in, const int* in_sizes, int n_in,
                              void* d_out, int out_size, void* d_ws, size_t ws_size,
                              hipStream_t stream)
{
    const float* y   = (const float*)d_in[0];
    const int*   ths = (const int*)d_in[1];
    uint2* ws2 = (uint2*)d_ws;

    uint2* FA = ws2;
    uint2* UA = ws2 + (size_t)NPIX;
    uint2* FB = ws2 + 2 * (size_t)NPIX;
    uint2* UB = ws2 + 3 * (size_t)NPIX;
    float* xout = (float*)d_out;

    dim3 block(256);
    dim3 grid(NBLK);

    // iter 0 (analytic) -> B
    sweep<0><<<grid, block, 0, stream>>>(y, ths, nullptr, nullptr, FB, UB, nullptr);
    // iters 1..8 alternate
    uint2 *fi = FB, *ui = UB, *fo = FA, *uo = UA;
    for (int it = 1; it <= 8; ++it) {
        sweep<1><<<grid, block, 0, stream>>>(y, ths, fi, ui, fo, uo, nullptr);
        uint2* t;
        t = fi; fi = fo; fo = t;
        t = ui; ui = uo; uo = t;
    }
    // iter 9: x only -> d_out
    sweep<2><<<grid, block, 0, stream>>>(y, ths, fi, ui, nullptr, nullptr, xout);
}

// Round 15
// 155.832 us; speedup vs baseline: 1.1873x; 1.0345x over previous
//
#include <hip/hip_runtime.h>
#include <hip/hip_fp16.h>
#include <math.h>

#define HH 512
#define WW 512
#define BB 4
#define NPIX (BB * HH * WW)

#define HS 4                 // core rows per wave (optimum: {2,4,8}->{185,160,211})
#define NSX 9                // sweep strips: 9 x 60 core cols; fused: 9 x 58
#define NBAND (HH / HS)      // 128
#define NWAVES (NSX * NBAND * BB)   // 4608
#define NBLK (NWAVES / 4)           // 1152

constexpr float TAUf   = 0.01f;
constexpr float RHOf   = 1.99f;
constexpr float SIGMAf = (float)(1.0 / 0.01 / 72.0);
constexpr float INV1PT = (float)(1.0 / 1.01);

__device__ __forceinline__ float SD(float v) { return __shfl_down(v, 1, 64); }    // lane+1
__device__ __forceinline__ unsigned SDu(unsigned v) { return __shfl_down(v, 1, 64); }
__device__ __forceinline__ float SUp(float v) { return __shfl_up(v, 1, 64); }     // lane-1

// Fused state record F (uint2): .x = half2(x2, r0), .y = half2(r1, y_half)
// u record (uint2): .x = half2(u0, u1), .y = half2(u2, u3)
// y_half bits pass through unchanged every iteration (no re-rounding drift).

// MODE: 1 = mid iter; 2 = last iter (x-only, f32 out)   [iter0+1 handled by fused01]
template <int MODE>
__global__ __launch_bounds__(256) void sweep(
    const float* __restrict__ y, const int* __restrict__ ths_p,
    const uint2* __restrict__ f_in, const uint2* __restrict__ u_in,
    uint2* __restrict__ f_out, uint2* __restrict__ u_out,
    float* __restrict__ xout)
{
    const int tid  = threadIdx.x;
    const int lane = tid & 63;
    const int wid  = blockIdx.x * 4 + (tid >> 6);
    const int sx   = wid % NSX;
    const int t2   = wid / NSX;
    const int band = t2 & (NBAND - 1);
    const int b    = t2 / NBAND;
    const int R0   = band * HS;
    const int w    = sx * 60 - 2 + lane;
    const int boff = b * (HH * WW);
    const bool wok = ((unsigned)w) < (unsigned)WW;
    const float mA = (w >= 1 && w < WW) ? 1.f : 0.f;
    const float mB = (w >= 0 && w < WW - 1) ? 1.f : 0.f;
    const bool cok = (lane >= 2) && (lane < 62) && (w < WW);

    const float ths  = (float)ths_p[0];
    const float tl1_ = TAUf * (ths * 0.1f);
    const float l2_  = ths * 0.15f;

    float uf0[4], uf1[4], uf2[4], uf3[4];
    unsigned u12r[4];
    float i0r[2], i1r[2];
    float sr[2], t1r[2];
    float v0r[4], v1r[2];
    #pragma unroll
    for (int q = 0; q < 4; ++q) { uf0[q]=uf1[q]=uf2[q]=uf3[q]=0.f; v0r[q]=0.f; u12r[q]=0u; }
    i0r[0]=i0r[1]=i1r[0]=i1r[1]=0.f;
    sr[0]=sr[1]=0.f; t1r[0]=t1r[1]=0.f; v1r[0]=v1r[1]=0.f;

    auto uload = [&](int row) -> uint2 {
        uint2 z; z.x = 0u; z.y = 0u;
        if (((unsigned)row) < (unsigned)HH && wok)
            z = u_in[(size_t)(boff + row * WW + w)];
        return z;
    };
    auto fload = [&](int row) -> uint2 {
        uint2 z; z.x = 0u; z.y = 0u;
        if (((unsigned)row) < (unsigned)HH && wok)
            z = f_in[(size_t)(boff + row * WW + w)];
        return z;
    };
    auto unpk = [&](int slot, uint2 raw) {
        __half2 lo = *(reinterpret_cast<__half2*>(&raw.x));
        __half2 hi = *(reinterpret_cast<__half2*>(&raw.y));
        uf0[slot] = __low2float(lo); uf1[slot] = __high2float(lo);
        uf2[slot] = __low2float(hi); uf3[slot] = __high2float(hi);
        u12r[slot] = (raw.x >> 16) | (raw.y << 16);
    };
    auto compI = [&](int rr, int islot, int c, int d, int uu_) {
        if (((unsigned)rr) < (unsigned)HH) {
            float hD  = (rr < HH - 1) ? 1.f : 0.f;
            unsigned pp = SDu(u12r[c]);
            __half2 ph = *(reinterpret_cast<__half2*>(&pp));
            float u1n = __low2float(ph);
            float u2n = __high2float(ph);
            i0r[islot] = uf0[c] - uf0[d] - u1n + mA * uf1[c];
            i1r[islot] = uf2[c] - u2n - hD * uf3[c] + uf3[uu_];
        } else { i0r[islot] = 0.f; i1r[islot] = 0.f; }
    };

    if (MODE == 2) {
        unpk(2, uload(R0 - 2));
        unpk(3, uload(R0 - 1));
        unpk(0, uload(R0));
        compI(R0 - 1, 1, 3, 0, 2);
        uint2 puA = uload(R0 + 1);
        uint2 puB = uload(R0 + 2);
        uint2 pfA = fload(R0);
        uint2 pfB = fload(R0 + 1);
        #pragma unroll
        for (int k = 0; k < HS; ++k) {
            const int rr = R0 + k;
            unpk((k + 1) & 3, puA);
            puA = puB;
            if (k < HS - 2) puB = uload(R0 + k + 3);
            __half2 lo = *(reinterpret_cast<__half2*>(&pfA.x));
            __half2 hi = *(reinterpret_cast<__half2*>(&pfA.y));
            float x2v = __low2float(lo);
            float yv  = __high2float(hi);
            pfA = pfB;
            if (k < HS - 2) pfB = fload(R0 + k + 2);
            compI(rr, k & 1, k & 3, (k + 1) & 3, (k + 3) & 3);
            float hD = (rr < HH - 1) ? 1.f : 0.f;
            float i0c = i0r[k & 1], i1c = i1r[k & 1], i1u = i1r[(k + 1) & 1];
            float i0l = SUp(i0c);
            float na = TAUf * (mA * i0l - mB * i0c + i1u - hD * i1c);
            float x = (x2v - na + TAUf * yv) * INV1PT;
            if (cok) xout[boff + rr * WW + w] = x2v + RHOf * (x - x2v);
        }
        return;
    }

    auto compS = [&](int rr, int isc, int isp,
                     float yv, float x2v, float r20v, float r21v, unsigned yraw,
                     bool coreRow, float &sOut, float &t0Out, float &t1Out) {
        if (((unsigned)rr) < (unsigned)HH) {
            float hD = (rr < HH - 1) ? 1.f : 0.f;
            float i0c = i0r[isc], i1c = i1r[isc], i1u = i1r[isp];
            float i0l = SUp(i0c);
            float na = TAUf * (mA * i0l - mB * i0c + i1u - hD * i1c);
            float x = (x2v - na + TAUf * yv) * INV1PT;
            float rr0 = r20v + TAUf * i0c;
            float rr1 = r21v + TAUf * i1c;
            float d = rr0 * rr0 + rr1 * rr1;
            float rinv = fminf(tl1_ * __builtin_amdgcn_rsqf(d), 1.0f);
            float r0 = rr0 - rr0 * rinv;
            float r1 = rr1 - rr1 * rinv;
            sOut  = 2.f * x  - x2v;
            t0Out = 2.f * r0 - r20v;
            t1Out = 2.f * r1 - r21v;
            if (coreRow && cok) {
                int idx = boff + rr * WW + w;
                __half2 lo2 = __floats2half2_rn(x2v + RHOf * (x - x2v),
                                                r20v + RHOf * (r0 - r20v));
                unsigned r1b = (unsigned)__half_as_ushort(
                    __float2half(r21v + RHOf * (r1 - r21v)));
                uint2 st; st.x = *(unsigned*)&lo2; st.y = r1b | (yraw << 16);
                f_out[(size_t)idx] = st;
            }
        } else { sOut = 0.f; t0Out = 0.f; t1Out = 0.f; }
    };

    auto compU = [&](int ro, int v0c_s, int v0u_s, int v1c_s, int v1d_s, int uslot) {
        float hD  = (ro < HH - 1) ? 1.f : 0.f;
        float v0c = v0r[v0c_s], v0u = v0r[v0u_s];
        float v1c = v1r[v1c_s], v1d = v1r[v1d_s];
        float v0l = SUp(v0c);
        float v1l = SUp(v1c);
        float G0 = v0c - v0u;
        float G1 = mA * (v0c - v0l);
        float G2 = v1c - mA * v1l;
        float G3 = hD * (v1d - v1c);
        float u0v = uf0[uslot], u1v = uf1[uslot], u2v = uf2[uslot], u3v = uf3[uslot];
        float uu0 = u0v + SIGMAf * G0;
        float uu1 = u1v + SIGMAf * G1;
        float uu2 = u2v + SIGMAf * G2;
        float uu3 = u3v + SIGMAf * G3;
        float d = uu0 * uu0 + uu1 * uu1 + uu2 * uu2 + uu3 * uu3;
        float ui = fminf(l2_ * __builtin_amdgcn_rsqf(d), 1.0f);
        if (cok) {
            int idx = boff + ro * WW + w;
            __half2 lo = __floats2half2_rn(u0v + RHOf * (uu0 * ui - u0v),
                                           u1v + RHOf * (uu1 * ui - u1v));
            __half2 hi = __floats2half2_rn(u2v + RHOf * (uu2 * ui - u2v),
                                           u3v + RHOf * (uu3 * ui - u3v));
            uint2 st; st.x = *(unsigned*)&lo; st.y = *(unsigned*)&hi;
            u_out[(size_t)idx] = st;
        }
    };

    uint2 puA, puB, pfA, pfB;
    puA.x = puA.y = puB.x = puB.y = 0u;
    pfA.x = pfA.y = pfB.x = pfB.y = 0u;
    unpk(1, uload(R0 - 3));
    unpk(2, uload(R0 - 2));
    unpk(3, uload(R0 - 1));
    compI(R0 - 2, 0, 2, 3, 1);
    puA = uload(R0);
    puB = uload(R0 + 1);
    pfA = fload(R0 - 1);
    pfB = fload(R0);

    #pragma unroll
    for (int k = 0; k < HS + 3; ++k) {
        const int rr = R0 - 1 + k;
        unpk(k & 3, puA);
        puA = puB;
        if (k <= HS) puB = uload(R0 + k + 2);
        __half2 lo = *(reinterpret_cast<__half2*>(&pfA.x));
        __half2 hi = *(reinterpret_cast<__half2*>(&pfA.y));
        float x2v  = __low2float(lo);
        float r20v = __high2float(lo);
        float r21v = __low2float(hi);
        float yv   = __high2float(hi);
        unsigned yraw = pfA.y >> 16;
        pfA = pfB;
        if (k <= HS) pfB = fload(R0 + k + 1);

        compI(rr, (k + 1) & 1, (k + 3) & 3, k & 3, (k + 2) & 3);

        float sN, t0N, t1N;
        compS(rr, (k + 1) & 1, k & 1, yv, x2v, r20v, r21v, yraw,
              (k >= 1 && k <= HS), sN, t0N, t1N);

        {
            float sPrev  = sr[k & 1];
            float t1Prev = t1r[k & 1];
            float hDm1   = (rr < HH) ? 1.f : 0.f;
            v0r[(k + 3) & 3] = mB * (SD(sN) - sN) - t0N;
            v1r[k & 1]       = hDm1 * (sN - sPrev) - t1Prev;
            sr[(k + 1) & 1]  = sN;
            t1r[(k + 1) & 1] = t1N;
        }

        if (k >= 3) compU(R0 - 3 + k, (k + 1) & 3, k & 3, (k + 1) & 1, k & 1,
                          (k + 1) & 3);
    }
}

// ---------------------------------------------------------------------------
// fused01: iterations 0 (analytic) + 1 in one kernel. 58-col cores (lanes
// 3..60): each in-register iteration loses ~1 lane/side; 9x58 = 522 >= 512.
// Producer (s0 = y -> v0_0/v1_0 rings -> u0' fp16-rounded into uf rings)
// runs 6 stages ahead of the standard iter-1 pipeline. Bit-faithful to the
// 2-dispatch path (same fp16 roundings).
// ---------------------------------------------------------------------------
__global__ __launch_bounds__(256) void fused01(
    const float* __restrict__ y, const int* __restrict__ ths_p,
    uint2* __restrict__ f_out, uint2* __restrict__ u_out)
{
    const int tid  = threadIdx.x;
    const int lane = tid & 63;
    const int wid  = blockIdx.x * 4 + (tid >> 6);
    const int sx   = wid % NSX;
    const int t2   = wid / NSX;
    const int band = t2 & (NBAND - 1);
    const int b    = t2 / NBAND;
    const int R0   = band * HS;
    const int w    = sx * 58 - 3 + lane;
    const int boff = b * (HH * WW);
    const bool wok = ((unsigned)w) < (unsigned)WW;
    const float mA = (w >= 1 && w < WW) ? 1.f : 0.f;
    const float mB = (w >= 0 && w < WW - 1) ? 1.f : 0.f;
    const bool cok = (lane >= 3) && (lane <= 60) && (w < WW);

    const float ths  = (float)ths_p[0];
    const float tl1_ = TAUf * (ths * 0.1f);
    const float l2_  = ths * 0.15f;

    // iter-0 producer rings
    float p0r[4];                 // v0_0(row), slot row&3 (= j&3 at write)
    float p1r[2];                 // v1_0(row), slot row&1
    float yD1 = 0.f, yD2 = 0.f, yD3 = 0.f;   // y(p-1), y(p-2), y(p-3)

    // iter-1 rings (same as sweep)
    float uf0[4], uf1[4], uf2[4], uf3[4];
    unsigned u12r[4];
    float i0r[2], i1r[2];
    float sr[2], t1r[2];
    float v0r[4], v1r[2];
    #pragma unroll
    for (int q = 0; q < 4; ++q) {
        uf0[q]=uf1[q]=uf2[q]=uf3[q]=0.f; v0r[q]=0.f; u12r[q]=0u; p0r[q]=0.f;
    }
    i0r[0]=i0r[1]=i1r[0]=i1r[1]=0.f;
    sr[0]=sr[1]=0.f; t1r[0]=t1r[1]=0.f; v1r[0]=v1r[1]=0.f; p1r[0]=p1r[1]=0.f;

    auto yload = [&](int row) -> float {
        return (((unsigned)row) < (unsigned)HH && wok)
                   ? y[boff + row * WW + w] : 0.f;
    };
    auto unpk = [&](int slot, uint2 raw) {
        __half2 lo = *(reinterpret_cast<__half2*>(&raw.x));
        __half2 hi = *(reinterpret_cast<__half2*>(&raw.y));
        uf0[slot] = __low2float(lo); uf1[slot] = __high2float(lo);
        uf2[slot] = __low2float(hi); uf3[slot] = __high2float(hi);
        u12r[slot] = (raw.x >> 16) | (raw.y << 16);
    };
    auto compI = [&](int rr, int islot, int c, int d, int uu_) {
        if (((unsigned)rr) < (unsigned)HH) {
            float hD  = (rr < HH - 1) ? 1.f : 0.f;
            unsigned pp = SDu(u12r[c]);
            __half2 ph = *(reinterpret_cast<__half2*>(&pp));
            float u1n = __low2float(ph);
            float u2n = __high2float(ph);
            i0r[islot] = uf0[c] - uf0[d] - u1n + mA * uf1[c];
            i1r[islot] = uf2[c] - u2n - hD * uf3[c] + uf3[uu_];
        } else { i0r[islot] = 0.f; i1r[islot] = 0.f; }
    };

    // 2-deep y prefetch: consume row p = R0-4+j at stage j
    float pyA = yload(R0 - 4);
    float pyB = yload(R0 - 3);

    #pragma unroll
    for (int j = 0; j < HS + 9; ++j) {
        const int p = R0 - 4 + j;             // producer row
        float yp = pyA; pyA = pyB;
        if (j <= HS + 6) pyB = yload(R0 - 2 + j);

        // ---- producer: v0_0(p), v1_0(p-1) (t_0 = 0) ----
        p0r[j & 3]       = mB * (SD(yp) - yp);
        p1r[(j + 1) & 1] = ((p < HH) ? 1.f : 0.f) * (yp - yD1);

        // ---- u0'(ro = R0-6+j): needs v0_0(ro-1..ro), v1_0(ro..ro+1) ----
        if (j >= 3) {
            const int ro = R0 - 6 + j;
            float hD  = (ro < HH - 1) ? 1.f : 0.f;
            float v0c = p0r[(j + 2) & 3], v0u = p0r[(j + 1) & 3];
            float v1c = p1r[j & 1],       v1d = p1r[(j + 1) & 1];
            float G0 = v0c - v0u;
            float G1 = mA * (v0c - SUp(v0c));
            float G2 = v1c - mA * SUp(v1c);
            float G3 = hD * (v1d - v1c);
            float uu0 = SIGMAf * G0, uu1 = SIGMAf * G1;
            float uu2 = SIGMAf * G2, uu3 = SIGMAf * G3;
            float d = uu0*uu0 + uu1*uu1 + uu2*uu2 + uu3*uu3;
            float ui = fminf(l2_ * __builtin_amdgcn_rsqf(d), 1.0f);
            __half2 lo = __floats2half2_rn(RHOf * (uu0 * ui), RHOf * (uu1 * ui));
            __half2 hi = __floats2half2_rn(RHOf * (uu2 * ui), RHOf * (uu3 * ui));
            uint2 st; st.x = *(unsigned*)&lo; st.y = *(unsigned*)&hi;
            unpk((j + 2) & 3, st);            // slot ro&3
        }

        // ---- iter-1 prologue compI at j==5 (rows R0-3..R0-1 now in rings) ----
        if (j == 5) compI(R0 - 2, 0, 2, 3, 1);

        // ---- iter-1 stage k = j-6 ----
        if (j >= 6) {
            const int k  = j - 6;
            const int rr = R0 - 1 + k;        // = R0 - 7 + j; y(rr) = yD3
            __half yh = __float2half(yD3);
            float yv  = __half2float(yh);     // x2v == yv (iter0: x2 = fp16(y))
            unsigned yraw = (unsigned)__half_as_ushort(yh);

            compI(rr, (k + 1) & 1, (k + 3) & 3, k & 3, (k + 2) & 3);

            float sN, t0N, t1N;
            {
                const bool coreRow = (k >= 1 && k <= HS);
                if (((unsigned)rr) < (unsigned)HH) {
                    float hD = (rr < HH - 1) ? 1.f : 0.f;
                    float i0c = i0r[(k + 1) & 1], i1c = i1r[(k + 1) & 1];
                    float i1u = i1r[k & 1];
                    float i0l = SUp(i0c);
                    float na = TAUf * (mA * i0l - mB * i0c + i1u - hD * i1c);
                    float x = (yv - na + TAUf * yv) * INV1PT;
                    float rr0 = TAUf * i0c;               // r2 = 0
                    float rr1 = TAUf * i1c;
                    float d2 = rr0*rr0 + rr1*rr1;
                    float rinv = fminf(tl1_ * __builtin_amdgcn_rsqf(d2), 1.0f);
                    float r0 = rr0 - rr0 * rinv;
                    float r1 = rr1 - rr1 * rinv;
                    sN  = 2.f * x - yv;
                    t0N = 2.f * r0;
                    t1N = 2.f * r1;
                    if (coreRow && cok) {
                        int idx = boff + rr * WW + w;
                        __half2 lo2 = __floats2half2_rn(yv + RHOf * (x - yv),
                                                        RHOf * r0);
                        unsigned r1b = (unsigned)__half_as_ushort(
                            __float2half(RHOf * r1));
                        uint2 st2; st2.x = *(unsigned*)&lo2;
                        st2.y = r1b | (yraw << 16);
                        f_out[(size_t)idx] = st2;
                    }
                } else { sN = 0.f; t0N = 0.f; t1N = 0.f; }
            }

            {
                float sPrev  = sr[k & 1];
                float t1Prev = t1r[k & 1];
                float hDm1   = (rr < HH) ? 1.f : 0.f;
                v0r[(k + 3) & 3] = mB * (SD(sN) - sN) - t0N;
                v1r[k & 1]       = hDm1 * (sN - sPrev) - t1Prev;
                sr[(k + 1) & 1]  = sN;
                t1r[(k + 1) & 1] = t1N;
            }

            if (k >= 3) {
                const int ro = R0 - 3 + k;
                float hD  = (ro < HH - 1) ? 1.f : 0.f;
                float v0c = v0r[(k + 1) & 3], v0u = v0r[k & 3];
                float v1c = v1r[(k + 1) & 1], v1d = v1r[k & 1];
                float v0l = SUp(v0c);
                float v1l = SUp(v1c);
                float G0 = v0c - v0u;
                float G1 = mA * (v0c - v0l);
                float G2 = v1c - mA * v1l;
                float G3 = hD * (v1d - v1c);
                const int us = (k + 1) & 3;   // uf row ro (u0'), written at j-3
                float u0v = uf0[us], u1v = uf1[us], u2v = uf2[us], u3v = uf3[us];
                float uu0 = u0v + SIGMAf * G0;
                float uu1 = u1v + SIGMAf * G1;
                float uu2 = u2v + SIGMAf * G2;
                float uu3 = u3v + SIGMAf * G3;
                float d = uu0*uu0 + uu1*uu1 + uu2*uu2 + uu3*uu3;
                float ui = fminf(l2_ * __builtin_amdgcn_rsqf(d), 1.0f);
                if (cok) {
                    int idx = boff + ro * WW + w;
                    __half2 lo = __floats2half2_rn(u0v + RHOf * (uu0 * ui - u0v),
                                                   u1v + RHOf * (uu1 * ui - u1v));
                    __half2 hi = __floats2half2_rn(u2v + RHOf * (uu2 * ui - u2v),
                                                   u3v + RHOf * (uu3 * ui - u3v));
                    uint2 st; st.x = *(unsigned*)&lo; st.y = *(unsigned*)&hi;
                    u_out[(size_t)idx] = st;
                }
            }
        }

        // rotate y delay line
        yD3 = yD2; yD2 = yD1; yD1 = yp;
    }
}

extern "C" void kernel_launch(void* const* d_in, const int* in_sizes, int n_in,
                              void* d_out, int out_size, void* d_ws, size_t ws_size,
                              hipStream_t stream)
{
    const float* y   = (const float*)d_in[0];
    const int*   ths = (const int*)d_in[1];
    uint2* ws2 = (uint2*)d_ws;

    uint2* FA = ws2;
    uint2* UA = ws2 + (size_t)NPIX;
    uint2* FB = ws2 + 2 * (size_t)NPIX;
    uint2* UB = ws2 + 3 * (size_t)NPIX;
    float* xout = (float*)d_out;

    dim3 block(256);
    dim3 grid(NBLK);

    // iters 0+1 fused (iter0 analytic, in-register) -> A
    fused01<<<grid, block, 0, stream>>>(y, ths, FA, UA);
    // iters 2..8: 7 mid dispatches
    uint2 *fi = FA, *ui = UA, *fo = FB, *uo = UB;
    for (int it = 2; it <= 8; ++it) {
        sweep<1><<<grid, block, 0, stream>>>(y, ths, fi, ui, fo, uo, nullptr);
        uint2* t;
        t = fi; fi = fo; fo = t;
        t = ui; ui = uo; uo = t;
    }
    // iter 9: x only -> d_out
    sweep<2><<<grid, block, 0, stream>>>(y, ths, fi, ui, nullptr, nullptr, xout);
}

// Round 16
// 151.646 us; speedup vs baseline: 1.2200x; 1.0276x over previous
//
#include <hip/hip_runtime.h>
#include <hip/hip_fp16.h>
#include <math.h>

#define HH 512
#define WW 512
#define BB 4
#define NPIX (BB * HH * WW)

#define HS 4                 // core rows per wave
#define NSX 9                // sweep strips: 9 x 60; fused01/fused89: 9 x 58
#define NBAND (HH / HS)      // 128
#define NWAVES (NSX * NBAND * BB)   // 4608
#define NBLK (NWAVES / 4)           // 1152

constexpr float TAUf   = 0.01f;
constexpr float RHOf   = 1.99f;
constexpr float SIGMAf = (float)(1.0 / 0.01 / 72.0);
constexpr float INV1PT = (float)(1.0 / 1.01);

__device__ __forceinline__ float SD(float v) { return __shfl_down(v, 1, 64); }    // lane+1
__device__ __forceinline__ unsigned SDu(unsigned v) { return __shfl_down(v, 1, 64); }
__device__ __forceinline__ float SUp(float v) { return __shfl_up(v, 1, 64); }     // lane-1

// F record (uint2): .x = half2(x2, r0), .y = half2(r1, y_half)
// u record (uint2): .x = half2(u0, u1), .y = half2(u2, u3)

// MODE: 1 = mid iter; 2 = last iter (x-only, f32 out)
template <int MODE>
__global__ __launch_bounds__(256) void sweep(
    const float* __restrict__ y, const int* __restrict__ ths_p,
    const uint2* __restrict__ f_in, const uint2* __restrict__ u_in,
    uint2* __restrict__ f_out, uint2* __restrict__ u_out,
    float* __restrict__ xout)
{
    const int tid  = threadIdx.x;
    const int lane = tid & 63;
    const int wid  = blockIdx.x * 4 + (tid >> 6);
    const int sx   = wid % NSX;
    const int t2   = wid / NSX;
    const int band = t2 & (NBAND - 1);
    const int b    = t2 / NBAND;
    const int R0   = band * HS;
    const int w    = sx * 60 - 2 + lane;
    const int boff = b * (HH * WW);
    const bool wok = ((unsigned)w) < (unsigned)WW;
    const float mA = (w >= 1 && w < WW) ? 1.f : 0.f;
    const float mB = (w >= 0 && w < WW - 1) ? 1.f : 0.f;
    const bool cok = (lane >= 2) && (lane < 62) && (w < WW);

    const float ths  = (float)ths_p[0];
    const float tl1_ = TAUf * (ths * 0.1f);
    const float l2_  = ths * 0.15f;

    float uf0[4], uf1[4], uf2[4], uf3[4];
    unsigned u12r[4];
    float i0r[2], i1r[2];
    float sr[2], t1r[2];
    float v0r[4], v1r[2];
    #pragma unroll
    for (int q = 0; q < 4; ++q) { uf0[q]=uf1[q]=uf2[q]=uf3[q]=0.f; v0r[q]=0.f; u12r[q]=0u; }
    i0r[0]=i0r[1]=i1r[0]=i1r[1]=0.f;
    sr[0]=sr[1]=0.f; t1r[0]=t1r[1]=0.f; v1r[0]=v1r[1]=0.f;

    auto uload = [&](int row) -> uint2 {
        uint2 z; z.x = 0u; z.y = 0u;
        if (((unsigned)row) < (unsigned)HH && wok)
            z = u_in[(size_t)(boff + row * WW + w)];
        return z;
    };
    auto fload = [&](int row) -> uint2 {
        uint2 z; z.x = 0u; z.y = 0u;
        if (((unsigned)row) < (unsigned)HH && wok)
            z = f_in[(size_t)(boff + row * WW + w)];
        return z;
    };
    auto unpk = [&](int slot, uint2 raw) {
        __half2 lo = *(reinterpret_cast<__half2*>(&raw.x));
        __half2 hi = *(reinterpret_cast<__half2*>(&raw.y));
        uf0[slot] = __low2float(lo); uf1[slot] = __high2float(lo);
        uf2[slot] = __low2float(hi); uf3[slot] = __high2float(hi);
        u12r[slot] = (raw.x >> 16) | (raw.y << 16);
    };
    auto compI = [&](int rr, int islot, int c, int d, int uu_) {
        if (((unsigned)rr) < (unsigned)HH) {
            float hD  = (rr < HH - 1) ? 1.f : 0.f;
            unsigned pp = SDu(u12r[c]);
            __half2 ph = *(reinterpret_cast<__half2*>(&pp));
            float u1n = __low2float(ph);
            float u2n = __high2float(ph);
            i0r[islot] = uf0[c] - uf0[d] - u1n + mA * uf1[c];
            i1r[islot] = uf2[c] - u2n - hD * uf3[c] + uf3[uu_];
        } else { i0r[islot] = 0.f; i1r[islot] = 0.f; }
    };

    if (MODE == 2) {
        unpk(2, uload(R0 - 2));
        unpk(3, uload(R0 - 1));
        unpk(0, uload(R0));
        compI(R0 - 1, 1, 3, 0, 2);
        uint2 puA = uload(R0 + 1);
        uint2 puB = uload(R0 + 2);
        uint2 pfA = fload(R0);
        uint2 pfB = fload(R0 + 1);
        #pragma unroll
        for (int k = 0; k < HS; ++k) {
            const int rr = R0 + k;
            unpk((k + 1) & 3, puA);
            puA = puB;
            if (k < HS - 2) puB = uload(R0 + k + 3);
            __half2 lo = *(reinterpret_cast<__half2*>(&pfA.x));
            __half2 hi = *(reinterpret_cast<__half2*>(&pfA.y));
            float x2v = __low2float(lo);
            float yv  = __high2float(hi);
            pfA = pfB;
            if (k < HS - 2) pfB = fload(R0 + k + 2);
            compI(rr, k & 1, k & 3, (k + 1) & 3, (k + 3) & 3);
            float hD = (rr < HH - 1) ? 1.f : 0.f;
            float i0c = i0r[k & 1], i1c = i1r[k & 1], i1u = i1r[(k + 1) & 1];
            float i0l = SUp(i0c);
            float na = TAUf * (mA * i0l - mB * i0c + i1u - hD * i1c);
            float x = (x2v - na + TAUf * yv) * INV1PT;
            if (cok) xout[boff + rr * WW + w] = x2v + RHOf * (x - x2v);
        }
        return;
    }

    auto compS = [&](int rr, int isc, int isp,
                     float yv, float x2v, float r20v, float r21v, unsigned yraw,
                     bool coreRow, float &sOut, float &t0Out, float &t1Out) {
        if (((unsigned)rr) < (unsigned)HH) {
            float hD = (rr < HH - 1) ? 1.f : 0.f;
            float i0c = i0r[isc], i1c = i1r[isc], i1u = i1r[isp];
            float i0l = SUp(i0c);
            float na = TAUf * (mA * i0l - mB * i0c + i1u - hD * i1c);
            float x = (x2v - na + TAUf * yv) * INV1PT;
            float rr0 = r20v + TAUf * i0c;
            float rr1 = r21v + TAUf * i1c;
            float d = rr0 * rr0 + rr1 * rr1;
            float rinv = fminf(tl1_ * __builtin_amdgcn_rsqf(d), 1.0f);
            float r0 = rr0 - rr0 * rinv;
            float r1 = rr1 - rr1 * rinv;
            sOut  = 2.f * x  - x2v;
            t0Out = 2.f * r0 - r20v;
            t1Out = 2.f * r1 - r21v;
            if (coreRow && cok) {
                int idx = boff + rr * WW + w;
                __half2 lo2 = __floats2half2_rn(x2v + RHOf * (x - x2v),
                                                r20v + RHOf * (r0 - r20v));
                unsigned r1b = (unsigned)__half_as_ushort(
                    __float2half(r21v + RHOf * (r1 - r21v)));
                uint2 st; st.x = *(unsigned*)&lo2; st.y = r1b | (yraw << 16);
                f_out[(size_t)idx] = st;
            }
        } else { sOut = 0.f; t0Out = 0.f; t1Out = 0.f; }
    };

    auto compU = [&](int ro, int v0c_s, int v0u_s, int v1c_s, int v1d_s, int uslot) {
        float hD  = (ro < HH - 1) ? 1.f : 0.f;
        float v0c = v0r[v0c_s], v0u = v0r[v0u_s];
        float v1c = v1r[v1c_s], v1d = v1r[v1d_s];
        float v0l = SUp(v0c);
        float v1l = SUp(v1c);
        float G0 = v0c - v0u;
        float G1 = mA * (v0c - v0l);
        float G2 = v1c - mA * v1l;
        float G3 = hD * (v1d - v1c);
        float u0v = uf0[uslot], u1v = uf1[uslot], u2v = uf2[uslot], u3v = uf3[uslot];
        float uu0 = u0v + SIGMAf * G0;
        float uu1 = u1v + SIGMAf * G1;
        float uu2 = u2v + SIGMAf * G2;
        float uu3 = u3v + SIGMAf * G3;
        float d = uu0 * uu0 + uu1 * uu1 + uu2 * uu2 + uu3 * uu3;
        float ui = fminf(l2_ * __builtin_amdgcn_rsqf(d), 1.0f);
        if (cok) {
            int idx = boff + ro * WW + w;
            __half2 lo = __floats2half2_rn(u0v + RHOf * (uu0 * ui - u0v),
                                           u1v + RHOf * (uu1 * ui - u1v));
            __half2 hi = __floats2half2_rn(u2v + RHOf * (uu2 * ui - u2v),
                                           u3v + RHOf * (uu3 * ui - u3v));
            uint2 st; st.x = *(unsigned*)&lo; st.y = *(unsigned*)&hi;
            u_out[(size_t)idx] = st;
        }
    };

    uint2 puA, puB, pfA, pfB;
    puA.x = puA.y = puB.x = puB.y = 0u;
    pfA.x = pfA.y = pfB.x = pfB.y = 0u;
    unpk(1, uload(R0 - 3));
    unpk(2, uload(R0 - 2));
    unpk(3, uload(R0 - 1));
    compI(R0 - 2, 0, 2, 3, 1);
    puA = uload(R0);
    puB = uload(R0 + 1);
    pfA = fload(R0 - 1);
    pfB = fload(R0);

    #pragma unroll
    for (int k = 0; k < HS + 3; ++k) {
        const int rr = R0 - 1 + k;
        unpk(k & 3, puA);
        puA = puB;
        if (k <= HS) puB = uload(R0 + k + 2);
        __half2 lo = *(reinterpret_cast<__half2*>(&pfA.x));
        __half2 hi = *(reinterpret_cast<__half2*>(&pfA.y));
        float x2v  = __low2float(lo);
        float r20v = __high2float(lo);
        float r21v = __low2float(hi);
        float yv   = __high2float(hi);
        unsigned yraw = pfA.y >> 16;
        pfA = pfB;
        if (k <= HS) pfB = fload(R0 + k + 1);

        compI(rr, (k + 1) & 1, (k + 3) & 3, k & 3, (k + 2) & 3);

        float sN, t0N, t1N;
        compS(rr, (k + 1) & 1, k & 1, yv, x2v, r20v, r21v, yraw,
              (k >= 1 && k <= HS), sN, t0N, t1N);

        {
            float sPrev  = sr[k & 1];
            float t1Prev = t1r[k & 1];
            float hDm1   = (rr < HH) ? 1.f : 0.f;
            v0r[(k + 3) & 3] = mB * (SD(sN) - sN) - t0N;
            v1r[k & 1]       = hDm1 * (sN - sPrev) - t1Prev;
            sr[(k + 1) & 1]  = sN;
            t1r[(k + 1) & 1] = t1N;
        }

        if (k >= 3) compU(R0 - 3 + k, (k + 1) & 3, k & 3, (k + 1) & 1, k & 1,
                          (k + 1) & 3);
    }
}

// ---------------------------------------------------------------------------
// fused01: iterations 0 (analytic) + 1. 58-col cores (lanes 3..60).
// ---------------------------------------------------------------------------
__global__ __launch_bounds__(256) void fused01(
    const float* __restrict__ y, const int* __restrict__ ths_p,
    uint2* __restrict__ f_out, uint2* __restrict__ u_out)
{
    const int tid  = threadIdx.x;
    const int lane = tid & 63;
    const int wid  = blockIdx.x * 4 + (tid >> 6);
    const int sx   = wid % NSX;
    const int t2   = wid / NSX;
    const int band = t2 & (NBAND - 1);
    const int b    = t2 / NBAND;
    const int R0   = band * HS;
    const int w    = sx * 58 - 3 + lane;
    const int boff = b * (HH * WW);
    const bool wok = ((unsigned)w) < (unsigned)WW;
    const float mA = (w >= 1 && w < WW) ? 1.f : 0.f;
    const float mB = (w >= 0 && w < WW - 1) ? 1.f : 0.f;
    const bool cok = (lane >= 3) && (lane <= 60) && (w < WW);

    const float ths  = (float)ths_p[0];
    const float tl1_ = TAUf * (ths * 0.1f);
    const float l2_  = ths * 0.15f;

    float p0r[4];
    float p1r[2];
    float yD1 = 0.f, yD2 = 0.f, yD3 = 0.f;

    float uf0[4], uf1[4], uf2[4], uf3[4];
    unsigned u12r[4];
    float i0r[2], i1r[2];
    float sr[2], t1r[2];
    float v0r[4], v1r[2];
    #pragma unroll
    for (int q = 0; q < 4; ++q) {
        uf0[q]=uf1[q]=uf2[q]=uf3[q]=0.f; v0r[q]=0.f; u12r[q]=0u; p0r[q]=0.f;
    }
    i0r[0]=i0r[1]=i1r[0]=i1r[1]=0.f;
    sr[0]=sr[1]=0.f; t1r[0]=t1r[1]=0.f; v1r[0]=v1r[1]=0.f; p1r[0]=p1r[1]=0.f;

    auto yload = [&](int row) -> float {
        return (((unsigned)row) < (unsigned)HH && wok)
                   ? y[boff + row * WW + w] : 0.f;
    };
    auto unpk = [&](int slot, uint2 raw) {
        __half2 lo = *(reinterpret_cast<__half2*>(&raw.x));
        __half2 hi = *(reinterpret_cast<__half2*>(&raw.y));
        uf0[slot] = __low2float(lo); uf1[slot] = __high2float(lo);
        uf2[slot] = __low2float(hi); uf3[slot] = __high2float(hi);
        u12r[slot] = (raw.x >> 16) | (raw.y << 16);
    };
    auto compI = [&](int rr, int islot, int c, int d, int uu_) {
        if (((unsigned)rr) < (unsigned)HH) {
            float hD  = (rr < HH - 1) ? 1.f : 0.f;
            unsigned pp = SDu(u12r[c]);
            __half2 ph = *(reinterpret_cast<__half2*>(&pp));
            float u1n = __low2float(ph);
            float u2n = __high2float(ph);
            i0r[islot] = uf0[c] - uf0[d] - u1n + mA * uf1[c];
            i1r[islot] = uf2[c] - u2n - hD * uf3[c] + uf3[uu_];
        } else { i0r[islot] = 0.f; i1r[islot] = 0.f; }
    };

    float pyA = yload(R0 - 4);
    float pyB = yload(R0 - 3);

    #pragma unroll
    for (int j = 0; j < HS + 9; ++j) {
        const int p = R0 - 4 + j;
        float yp = pyA; pyA = pyB;
        if (j <= HS + 6) pyB = yload(R0 - 2 + j);

        p0r[j & 3]       = mB * (SD(yp) - yp);
        p1r[(j + 1) & 1] = ((p < HH) ? 1.f : 0.f) * (yp - yD1);

        if (j >= 3) {
            const int ro = R0 - 6 + j;
            float hD  = (ro < HH - 1) ? 1.f : 0.f;
            float v0c = p0r[(j + 2) & 3], v0u = p0r[(j + 1) & 3];
            float v1c = p1r[j & 1],       v1d = p1r[(j + 1) & 1];
            float G0 = v0c - v0u;
            float G1 = mA * (v0c - SUp(v0c));
            float G2 = v1c - mA * SUp(v1c);
            float G3 = hD * (v1d - v1c);
            float uu0 = SIGMAf * G0, uu1 = SIGMAf * G1;
            float uu2 = SIGMAf * G2, uu3 = SIGMAf * G3;
            float d = uu0*uu0 + uu1*uu1 + uu2*uu2 + uu3*uu3;
            float ui = fminf(l2_ * __builtin_amdgcn_rsqf(d), 1.0f);
            __half2 lo = __floats2half2_rn(RHOf * (uu0 * ui), RHOf * (uu1 * ui));
            __half2 hi = __floats2half2_rn(RHOf * (uu2 * ui), RHOf * (uu3 * ui));
            uint2 st; st.x = *(unsigned*)&lo; st.y = *(unsigned*)&hi;
            unpk((j + 2) & 3, st);
        }

        if (j == 5) compI(R0 - 2, 0, 2, 3, 1);

        if (j >= 6) {
            const int k  = j - 6;
            const int rr = R0 - 1 + k;
            __half yh = __float2half(yD3);
            float yv  = __half2float(yh);
            unsigned yraw = (unsigned)__half_as_ushort(yh);

            compI(rr, (k + 1) & 1, (k + 3) & 3, k & 3, (k + 2) & 3);

            float sN, t0N, t1N;
            {
                const bool coreRow = (k >= 1 && k <= HS);
                if (((unsigned)rr) < (unsigned)HH) {
                    float hD = (rr < HH - 1) ? 1.f : 0.f;
                    float i0c = i0r[(k + 1) & 1], i1c = i1r[(k + 1) & 1];
                    float i1u = i1r[k & 1];
                    float i0l = SUp(i0c);
                    float na = TAUf * (mA * i0l - mB * i0c + i1u - hD * i1c);
                    float x = (yv - na + TAUf * yv) * INV1PT;
                    float rr0 = TAUf * i0c;
                    float rr1 = TAUf * i1c;
                    float d2 = rr0*rr0 + rr1*rr1;
                    float rinv = fminf(tl1_ * __builtin_amdgcn_rsqf(d2), 1.0f);
                    float r0 = rr0 - rr0 * rinv;
                    float r1 = rr1 - rr1 * rinv;
                    sN  = 2.f * x - yv;
                    t0N = 2.f * r0;
                    t1N = 2.f * r1;
                    if (coreRow && cok) {
                        int idx = boff + rr * WW + w;
                        __half2 lo2 = __floats2half2_rn(yv + RHOf * (x - yv),
                                                        RHOf * r0);
                        unsigned r1b = (unsigned)__half_as_ushort(
                            __float2half(RHOf * r1));
                        uint2 st2; st2.x = *(unsigned*)&lo2;
                        st2.y = r1b | (yraw << 16);
                        f_out[(size_t)idx] = st2;
                    }
                } else { sN = 0.f; t0N = 0.f; t1N = 0.f; }
            }

            {
                float sPrev  = sr[k & 1];
                float t1Prev = t1r[k & 1];
                float hDm1   = (rr < HH) ? 1.f : 0.f;
                v0r[(k + 3) & 3] = mB * (SD(sN) - sN) - t0N;
                v1r[k & 1]       = hDm1 * (sN - sPrev) - t1Prev;
                sr[(k + 1) & 1]  = sN;
                t1r[(k + 1) & 1] = t1N;
            }

            if (k >= 3) {
                const int ro = R0 - 3 + k;
                float hD  = (ro < HH - 1) ? 1.f : 0.f;
                float v0c = v0r[(k + 1) & 3], v0u = v0r[k & 3];
                float v1c = v1r[(k + 1) & 1], v1d = v1r[k & 1];
                float v0l = SUp(v0c);
                float v1l = SUp(v1c);
                float G0 = v0c - v0u;
                float G1 = mA * (v0c - v0l);
                float G2 = v1c - mA * v1l;
                float G3 = hD * (v1d - v1c);
                const int us = (k + 1) & 3;
                float u0v = uf0[us], u1v = uf1[us], u2v = uf2[us], u3v = uf3[us];
                float uu0 = u0v + SIGMAf * G0;
                float uu1 = u1v + SIGMAf * G1;
                float uu2 = u2v + SIGMAf * G2;
                float uu3 = u3v + SIGMAf * G3;
                float d = uu0*uu0 + uu1*uu1 + uu2*uu2 + uu3*uu3;
                float ui = fminf(l2_ * __builtin_amdgcn_rsqf(d), 1.0f);
                if (cok) {
                    int idx = boff + ro * WW + w;
                    __half2 lo = __floats2half2_rn(u0v + RHOf * (uu0 * ui - u0v),
                                                   u1v + RHOf * (uu1 * ui - u1v));
                    __half2 hi = __floats2half2_rn(u2v + RHOf * (uu2 * ui - u2v),
                                                   u3v + RHOf * (uu3 * ui - u3v));
                    uint2 st; st.x = *(unsigned*)&lo; st.y = *(unsigned*)&hi;
                    u_out[(size_t)idx] = st;
                }
            }
        }

        yD3 = yD2; yD2 = yD1; yD1 = yp;
    }
}

// ---------------------------------------------------------------------------
// fused89: iter 8 (full mid, producer P) + iter 9 (x-only, consumer C).
// Same 58-col geometry as fused01 (validity erosion: P ±2 lanes, C +SD/SUp
// -> core lanes 3..60). P = sweep-mid pipeline at R0p = R0-2, HSp = HS+3:
// compU covers u_mid rows [R0-2, R0+HS]; with LAG=6 the compU output at
// stage J is exactly the row C unpacks at stage J (direct handoff). F_mid
// rides a 4-slot row&3 ring (write lag 3). All fp16 roundings identical to
// the store/load path -> bit-faithful to the 2-dispatch version.
// ---------------------------------------------------------------------------
__global__ __launch_bounds__(256) void fused89(
    const int* __restrict__ ths_p,
    const uint2* __restrict__ f_in, const uint2* __restrict__ u_in,
    float* __restrict__ xout)
{
    const int tid  = threadIdx.x;
    const int lane = tid & 63;
    const int wid  = blockIdx.x * 4 + (tid >> 6);
    const int sx   = wid % NSX;
    const int t2   = wid / NSX;
    const int band = t2 & (NBAND - 1);
    const int b    = t2 / NBAND;
    const int R0   = band * HS;
    const int R0p  = R0 - 2;
    const int w    = sx * 58 - 3 + lane;
    const int boff = b * (HH * WW);
    const bool wok = ((unsigned)w) < (unsigned)WW;
    const float mA = (w >= 1 && w < WW) ? 1.f : 0.f;
    const float mB = (w >= 0 && w < WW - 1) ? 1.f : 0.f;
    const bool cokC = (lane >= 3) && (lane <= 60) && (w < WW);

    const float ths  = (float)ths_p[0];
    const float tl1_ = TAUf * (ths * 0.1f);
    const float l2_  = ths * 0.15f;

    constexpr int HSp = HS + 3;   // 7; P stages J = 0..HSp+2 (10 stages)

    // P rings
    float uf0[4], uf1[4], uf2[4], uf3[4];
    unsigned u12r[4];
    float i0r[2], i1r[2];
    float sr[2], t1r[2];
    float v0r[4], v1r[2];
    // C rings
    float cf0[4], cf1[4], cf2[4], cf3[4];
    unsigned c12[4];
    float ci0[2], ci1[2];
    uint2 fmid[4];
    #pragma unroll
    for (int q = 0; q < 4; ++q) {
        uf0[q]=uf1[q]=uf2[q]=uf3[q]=0.f; v0r[q]=0.f; u12r[q]=0u;
        cf0[q]=cf1[q]=cf2[q]=cf3[q]=0.f; c12[q]=0u;
        fmid[q].x = 0u; fmid[q].y = 0u;
    }
    i0r[0]=i0r[1]=i1r[0]=i1r[1]=0.f;
    ci0[0]=ci0[1]=ci1[0]=ci1[1]=0.f;
    sr[0]=sr[1]=0.f; t1r[0]=t1r[1]=0.f; v1r[0]=v1r[1]=0.f;

    auto uload = [&](int row) -> uint2 {
        uint2 z; z.x = 0u; z.y = 0u;
        if (((unsigned)row) < (unsigned)HH && wok)
            z = u_in[(size_t)(boff + row * WW + w)];
        return z;
    };
    auto fload = [&](int row) -> uint2 {
        uint2 z; z.x = 0u; z.y = 0u;
        if (((unsigned)row) < (unsigned)HH && wok)
            z = f_in[(size_t)(boff + row * WW + w)];
        return z;
    };
    auto unpk = [&](int slot, uint2 raw) {
        __half2 lo = *(reinterpret_cast<__half2*>(&raw.x));
        __half2 hi = *(reinterpret_cast<__half2*>(&raw.y));
        uf0[slot] = __low2float(lo); uf1[slot] = __high2float(lo);
        uf2[slot] = __low2float(hi); uf3[slot] = __high2float(hi);
        u12r[slot] = (raw.x >> 16) | (raw.y << 16);
    };
    auto compI = [&](int rr, int islot, int c, int d, int uu_) {
        if (((unsigned)rr) < (unsigned)HH) {
            float hD  = (rr < HH - 1) ? 1.f : 0.f;
            unsigned pp = SDu(u12r[c]);
            __half2 ph = *(reinterpret_cast<__half2*>(&pp));
            float u1n = __low2float(ph);
            float u2n = __high2float(ph);
            i0r[islot] = uf0[c] - uf0[d] - u1n + mA * uf1[c];
            i1r[islot] = uf2[c] - u2n - hD * uf3[c] + uf3[uu_];
        } else { i0r[islot] = 0.f; i1r[islot] = 0.f; }
    };
    auto cunpk = [&](int slot, uint2 raw) {
        __half2 lo = *(reinterpret_cast<__half2*>(&raw.x));
        __half2 hi = *(reinterpret_cast<__half2*>(&raw.y));
        cf0[slot] = __low2float(lo); cf1[slot] = __high2float(lo);
        cf2[slot] = __low2float(hi); cf3[slot] = __high2float(hi);
        c12[slot] = (raw.x >> 16) | (raw.y << 16);
    };
    auto ccompI = [&](int rr, int islot, int c, int d, int uu_) {
        if (((unsigned)rr) < (unsigned)HH) {
            float hD  = (rr < HH - 1) ? 1.f : 0.f;
            unsigned pp = SDu(c12[c]);
            __half2 ph = *(reinterpret_cast<__half2*>(&pp));
            float u1n = __low2float(ph);
            float u2n = __high2float(ph);
            ci0[islot] = cf0[c] - cf0[d] - u1n + mA * cf1[c];
            ci1[islot] = cf2[c] - u2n - hD * cf3[c] + cf3[uu_];
        } else { ci0[islot] = 0.f; ci1[islot] = 0.f; }
    };

    // ---- P prologue (sweep-mid at R0p) ----
    unpk(1, uload(R0p - 3));
    unpk(2, uload(R0p - 2));
    unpk(3, uload(R0p - 1));
    compI(R0p - 2, 0, 2, 3, 1);
    uint2 puA = uload(R0p);
    uint2 puB = uload(R0p + 1);
    uint2 pfA = fload(R0p - 1);
    uint2 pfB = fload(R0p);

    #pragma unroll
    for (int J = 0; J < HSp + 3; ++J) {       // J = 0..9
        const int rp = R0p - 1 + J;

        // ---- P stage ----
        unpk(J & 3, puA);
        puA = puB;
        if (J <= HSp) puB = uload(R0p + J + 2);
        __half2 flo = *(reinterpret_cast<__half2*>(&pfA.x));
        __half2 fhi = *(reinterpret_cast<__half2*>(&pfA.y));
        float x2v  = __low2float(flo);
        float r20v = __high2float(flo);
        float r21v = __low2float(fhi);
        float yv   = __high2float(fhi);
        unsigned yraw = pfA.y >> 16;
        pfA = pfB;
        if (J <= HSp) pfB = fload(R0p + J + 1);

        compI(rp, (J + 1) & 1, (J + 3) & 3, J & 3, (J + 2) & 3);

        float sN, t0N, t1N;
        if (((unsigned)rp) < (unsigned)HH) {
            float hD = (rp < HH - 1) ? 1.f : 0.f;
            float i0c = i0r[(J + 1) & 1], i1c = i1r[(J + 1) & 1];
            float i1u = i1r[J & 1];
            float i0l = SUp(i0c);
            float na = TAUf * (mA * i0l - mB * i0c + i1u - hD * i1c);
            float x = (x2v - na + TAUf * yv) * INV1PT;
            float rr0 = r20v + TAUf * i0c;
            float rr1 = r21v + TAUf * i1c;
            float d = rr0 * rr0 + rr1 * rr1;
            float rinv = fminf(tl1_ * __builtin_amdgcn_rsqf(d), 1.0f);
            float r0 = rr0 - rr0 * rinv;
            float r1 = rr1 - rr1 * rinv;
            sN  = 2.f * x  - x2v;
            t0N = 2.f * r0 - r20v;
            t1N = 2.f * r1 - r21v;
            if (J >= 3 && J <= HS + 2) {       // F_mid rows R0..R0+HS-1
                __half2 lo2 = __floats2half2_rn(x2v + RHOf * (x - x2v),
                                                r20v + RHOf * (r0 - r20v));
                unsigned r1b = (unsigned)__half_as_ushort(
                    __float2half(r21v + RHOf * (r1 - r21v)));
                uint2 st; st.x = *(unsigned*)&lo2; st.y = r1b | (yraw << 16);
                fmid[(J + 1) & 3] = st;        // slot = row rp & 3
            }
        } else { sN = 0.f; t0N = 0.f; t1N = 0.f; }

        {
            float sPrev  = sr[J & 1];
            float t1Prev = t1r[J & 1];
            float hDm1   = (rp < HH) ? 1.f : 0.f;
            v0r[(J + 3) & 3] = mB * (SD(sN) - sN) - t0N;
            v1r[J & 1]       = hDm1 * (sN - sPrev) - t1Prev;
            sr[(J + 1) & 1]  = sN;
            t1r[(J + 1) & 1] = t1N;
        }

        if (J >= 3) {
            // compU(ro = R0p-3+J = R0-5+J), handoff to C ring (slot ro&3)
            const int ro = R0p - 3 + J;
            float hD  = (ro < HH - 1) ? 1.f : 0.f;
            float v0c = v0r[(J + 1) & 3], v0u = v0r[J & 3];
            float v1c = v1r[(J + 1) & 1], v1d = v1r[J & 1];
            float v0l = SUp(v0c);
            float v1l = SUp(v1c);
            float G0 = v0c - v0u;
            float G1 = mA * (v0c - v0l);
            float G2 = v1c - mA * v1l;
            float G3 = hD * (v1d - v1c);
            const int us = (J + 1) & 3;
            float u0v = uf0[us], u1v = uf1[us], u2v = uf2[us], u3v = uf3[us];
            float uu0 = u0v + SIGMAf * G0;
            float uu1 = u1v + SIGMAf * G1;
            float uu2 = u2v + SIGMAf * G2;
            float uu3 = u3v + SIGMAf * G3;
            float d = uu0*uu0 + uu1*uu1 + uu2*uu2 + uu3*uu3;
            float ui = fminf(l2_ * __builtin_amdgcn_rsqf(d), 1.0f);
            uint2 st; st.x = 0u; st.y = 0u;
            if (((unsigned)ro) < (unsigned)HH) {
                __half2 lo = __floats2half2_rn(u0v + RHOf * (uu0 * ui - u0v),
                                               u1v + RHOf * (uu1 * ui - u1v));
                __half2 hi = __floats2half2_rn(u2v + RHOf * (uu2 * ui - u2v),
                                               u3v + RHOf * (uu3 * ui - u3v));
                st.x = *(unsigned*)&lo; st.y = *(unsigned*)&hi;
            }
            cunpk((J + 3) & 3, st);            // slot = ro & 3
        }

        // ---- C part ----
        if (J == 5) ccompI(R0 - 1, 1, 3, 0, 2);
        if (J >= 6) {
            const int kc = J - 6;
            const int rc = R0 + kc;
            ccompI(rc, kc & 1, kc & 3, (kc + 1) & 3, (kc + 3) & 3);
            uint2 fm = fmid[(J + 2) & 3];       // row rc, written at J-3
            __half2 mlo = *(reinterpret_cast<__half2*>(&fm.x));
            __half2 mhi = *(reinterpret_cast<__half2*>(&fm.y));
            float cx2 = __low2float(mlo);
            float cyv = __high2float(mhi);
            float hD = (rc < HH - 1) ? 1.f : 0.f;
            float i0c = ci0[kc & 1], i1c = ci1[kc & 1], i1u = ci1[(kc + 1) & 1];
            float i0l = SUp(i0c);
            float na = TAUf * (mA * i0l - mB * i0c + i1u - hD * i1c);
            float x = (cx2 - na + TAUf * cyv) * INV1PT;
            if (cokC) xout[boff + rc * WW + w] = cx2 + RHOf * (x - cx2);
        }
    }
}

extern "C" void kernel_launch(void* const* d_in, const int* in_sizes, int n_in,
                              void* d_out, int out_size, void* d_ws, size_t ws_size,
                              hipStream_t stream)
{
    const float* y   = (const float*)d_in[0];
    const int*   ths = (const int*)d_in[1];
    uint2* ws2 = (uint2*)d_ws;

    uint2* FA = ws2;
    uint2* UA = ws2 + (size_t)NPIX;
    uint2* FB = ws2 + 2 * (size_t)NPIX;
    uint2* UB = ws2 + 3 * (size_t)NPIX;
    float* xout = (float*)d_out;

    dim3 block(256);
    dim3 grid(NBLK);

    // iters 0+1 fused -> A
    fused01<<<grid, block, 0, stream>>>(y, ths, FA, UA);
    // iters 2..7: 6 mid dispatches (A->B->A->B->A->B->A)
    uint2 *fi = FA, *ui = UA, *fo = FB, *uo = UB;
    for (int it = 2; it <= 7; ++it) {
        sweep<1><<<grid, block, 0, stream>>>(y, ths, fi, ui, fo, uo, nullptr);
        uint2* t;
        t = fi; fi = fo; fo = t;
        t = ui; ui = uo; uo = t;
    }
    // iters 8+9 fused: reads state after iter 7 -> xout
    fused89<<<grid, block, 0, stream>>>(ths, fi, ui, xout);
}

// Round 17
// 137.035 us; speedup vs baseline: 1.3501x; 1.1066x over previous
//
#include <hip/hip_runtime.h>
#include <hip/hip_fp16.h>
#include <math.h>

#define HH 512
#define WW 512
#define BB 4
#define NPIX (BB * HH * WW)

#define HS 4                 // core rows per wave
#define NSX 9                // sweep strips: 9 x 60; fused01/fused89: 9 x 58
#define NBAND (HH / HS)      // 128
#define NWAVES (NSX * NBAND * BB)   // 4608
#define NBLK (NWAVES / 4)           // 1152
#define BPR (NBLK / 8)              // 144 blocks per XCD-region

constexpr float TAUf   = 0.01f;
constexpr float RHOf   = 1.99f;
constexpr float SIGMAf = (float)(1.0 / 0.01 / 72.0);
constexpr float INV1PT = (float)(1.0 / 1.01);

__device__ __forceinline__ float SD(float v) { return __shfl_down(v, 1, 64); }    // lane+1
__device__ __forceinline__ unsigned SDu(unsigned v) { return __shfl_down(v, 1, 64); }
__device__ __forceinline__ float SUp(float v) { return __shfl_up(v, 1, 64); }     // lane-1

// XCD-locality swizzle: assuming blockIdx % 8 -> XCD round-robin, this gives
// XCD r the SAME contiguous 64-band (256-row) slab every dispatch, so the
// F/u ping-pong (2 MB/slab/buffer) stays in that XCD's private 4 MB L2
// across iterations. Pure permutation of wid -> zero correctness risk.
__device__ __forceinline__ int swiz_wid(int bid, int tid) {
    return (((bid & 7) * BPR) + (bid >> 3)) * 4 + (tid >> 6);
}

// F record (uint2): .x = half2(x2, r0), .y = half2(r1, y_half)
// u record (uint2): .x = half2(u0, u1), .y = half2(u2, u3)

// MODE: 1 = mid iter; 2 = last iter (x-only, f32 out)
template <int MODE>
__global__ __launch_bounds__(256) void sweep(
    const float* __restrict__ y, const int* __restrict__ ths_p,
    const uint2* __restrict__ f_in, const uint2* __restrict__ u_in,
    uint2* __restrict__ f_out, uint2* __restrict__ u_out,
    float* __restrict__ xout)
{
    const int tid  = threadIdx.x;
    const int lane = tid & 63;
    const int wid  = swiz_wid(blockIdx.x, tid);
    const int sx   = wid % NSX;
    const int t2   = wid / NSX;
    const int band = t2 & (NBAND - 1);
    const int b    = t2 / NBAND;
    const int R0   = band * HS;
    const int w    = sx * 60 - 2 + lane;
    const int boff = b * (HH * WW);
    const bool wok = ((unsigned)w) < (unsigned)WW;
    const float mA = (w >= 1 && w < WW) ? 1.f : 0.f;
    const float mB = (w >= 0 && w < WW - 1) ? 1.f : 0.f;
    const bool cok = (lane >= 2) && (lane < 62) && (w < WW);

    const float ths  = (float)ths_p[0];
    const float tl1_ = TAUf * (ths * 0.1f);
    const float l2_  = ths * 0.15f;

    float uf0[4], uf1[4], uf2[4], uf3[4];
    unsigned u12r[4];
    float i0r[2], i1r[2];
    float sr[2], t1r[2];
    float v0r[4], v1r[2];
    #pragma unroll
    for (int q = 0; q < 4; ++q) { uf0[q]=uf1[q]=uf2[q]=uf3[q]=0.f; v0r[q]=0.f; u12r[q]=0u; }
    i0r[0]=i0r[1]=i1r[0]=i1r[1]=0.f;
    sr[0]=sr[1]=0.f; t1r[0]=t1r[1]=0.f; v1r[0]=v1r[1]=0.f;

    auto uload = [&](int row) -> uint2 {
        uint2 z; z.x = 0u; z.y = 0u;
        if (((unsigned)row) < (unsigned)HH && wok)
            z = u_in[(size_t)(boff + row * WW + w)];
        return z;
    };
    auto fload = [&](int row) -> uint2 {
        uint2 z; z.x = 0u; z.y = 0u;
        if (((unsigned)row) < (unsigned)HH && wok)
            z = f_in[(size_t)(boff + row * WW + w)];
        return z;
    };
    auto unpk = [&](int slot, uint2 raw) {
        __half2 lo = *(reinterpret_cast<__half2*>(&raw.x));
        __half2 hi = *(reinterpret_cast<__half2*>(&raw.y));
        uf0[slot] = __low2float(lo); uf1[slot] = __high2float(lo);
        uf2[slot] = __low2float(hi); uf3[slot] = __high2float(hi);
        u12r[slot] = (raw.x >> 16) | (raw.y << 16);
    };
    auto compI = [&](int rr, int islot, int c, int d, int uu_) {
        if (((unsigned)rr) < (unsigned)HH) {
            float hD  = (rr < HH - 1) ? 1.f : 0.f;
            unsigned pp = SDu(u12r[c]);
            __half2 ph = *(reinterpret_cast<__half2*>(&pp));
            float u1n = __low2float(ph);
            float u2n = __high2float(ph);
            i0r[islot] = uf0[c] - uf0[d] - u1n + mA * uf1[c];
            i1r[islot] = uf2[c] - u2n - hD * uf3[c] + uf3[uu_];
        } else { i0r[islot] = 0.f; i1r[islot] = 0.f; }
    };

    if (MODE == 2) {
        unpk(2, uload(R0 - 2));
        unpk(3, uload(R0 - 1));
        unpk(0, uload(R0));
        compI(R0 - 1, 1, 3, 0, 2);
        uint2 puA = uload(R0 + 1);
        uint2 puB = uload(R0 + 2);
        uint2 pfA = fload(R0);
        uint2 pfB = fload(R0 + 1);
        #pragma unroll
        for (int k = 0; k < HS; ++k) {
            const int rr = R0 + k;
            unpk((k + 1) & 3, puA);
            puA = puB;
            if (k < HS - 2) puB = uload(R0 + k + 3);
            __half2 lo = *(reinterpret_cast<__half2*>(&pfA.x));
            __half2 hi = *(reinterpret_cast<__half2*>(&pfA.y));
            float x2v = __low2float(lo);
            float yv  = __high2float(hi);
            pfA = pfB;
            if (k < HS - 2) pfB = fload(R0 + k + 2);
            compI(rr, k & 1, k & 3, (k + 1) & 3, (k + 3) & 3);
            float hD = (rr < HH - 1) ? 1.f : 0.f;
            float i0c = i0r[k & 1], i1c = i1r[k & 1], i1u = i1r[(k + 1) & 1];
            float i0l = SUp(i0c);
            float na = TAUf * (mA * i0l - mB * i0c + i1u - hD * i1c);
            float x = (x2v - na + TAUf * yv) * INV1PT;
            if (cok) xout[boff + rr * WW + w] = x2v + RHOf * (x - x2v);
        }
        return;
    }

    auto compS = [&](int rr, int isc, int isp,
                     float yv, float x2v, float r20v, float r21v, unsigned yraw,
                     bool coreRow, float &sOut, float &t0Out, float &t1Out) {
        if (((unsigned)rr) < (unsigned)HH) {
            float hD = (rr < HH - 1) ? 1.f : 0.f;
            float i0c = i0r[isc], i1c = i1r[isc], i1u = i1r[isp];
            float i0l = SUp(i0c);
            float na = TAUf * (mA * i0l - mB * i0c + i1u - hD * i1c);
            float x = (x2v - na + TAUf * yv) * INV1PT;
            float rr0 = r20v + TAUf * i0c;
            float rr1 = r21v + TAUf * i1c;
            float d = rr0 * rr0 + rr1 * rr1;
            float rinv = fminf(tl1_ * __builtin_amdgcn_rsqf(d), 1.0f);
            float r0 = rr0 - rr0 * rinv;
            float r1 = rr1 - rr1 * rinv;
            sOut  = 2.f * x  - x2v;
            t0Out = 2.f * r0 - r20v;
            t1Out = 2.f * r1 - r21v;
            if (coreRow && cok) {
                int idx = boff + rr * WW + w;
                __half2 lo2 = __floats2half2_rn(x2v + RHOf * (x - x2v),
                                                r20v + RHOf * (r0 - r20v));
                unsigned r1b = (unsigned)__half_as_ushort(
                    __float2half(r21v + RHOf * (r1 - r21v)));
                uint2 st; st.x = *(unsigned*)&lo2; st.y = r1b | (yraw << 16);
                f_out[(size_t)idx] = st;
            }
        } else { sOut = 0.f; t0Out = 0.f; t1Out = 0.f; }
    };

    auto compU = [&](int ro, int v0c_s, int v0u_s, int v1c_s, int v1d_s, int uslot) {
        float hD  = (ro < HH - 1) ? 1.f : 0.f;
        float v0c = v0r[v0c_s], v0u = v0r[v0u_s];
        float v1c = v1r[v1c_s], v1d = v1r[v1d_s];
        float v0l = SUp(v0c);
        float v1l = SUp(v1c);
        float G0 = v0c - v0u;
        float G1 = mA * (v0c - v0l);
        float G2 = v1c - mA * v1l;
        float G3 = hD * (v1d - v1c);
        float u0v = uf0[uslot], u1v = uf1[uslot], u2v = uf2[uslot], u3v = uf3[uslot];
        float uu0 = u0v + SIGMAf * G0;
        float uu1 = u1v + SIGMAf * G1;
        float uu2 = u2v + SIGMAf * G2;
        float uu3 = u3v + SIGMAf * G3;
        float d = uu0 * uu0 + uu1 * uu1 + uu2 * uu2 + uu3 * uu3;
        float ui = fminf(l2_ * __builtin_amdgcn_rsqf(d), 1.0f);
        if (cok) {
            int idx = boff + ro * WW + w;
            __half2 lo = __floats2half2_rn(u0v + RHOf * (uu0 * ui - u0v),
                                           u1v + RHOf * (uu1 * ui - u1v));
            __half2 hi = __floats2half2_rn(u2v + RHOf * (uu2 * ui - u2v),
                                           u3v + RHOf * (uu3 * ui - u3v));
            uint2 st; st.x = *(unsigned*)&lo; st.y = *(unsigned*)&hi;
            u_out[(size_t)idx] = st;
        }
    };

    uint2 puA, puB, pfA, pfB;
    puA.x = puA.y = puB.x = puB.y = 0u;
    pfA.x = pfA.y = pfB.x = pfB.y = 0u;
    unpk(1, uload(R0 - 3));
    unpk(2, uload(R0 - 2));
    unpk(3, uload(R0 - 1));
    compI(R0 - 2, 0, 2, 3, 1);
    puA = uload(R0);
    puB = uload(R0 + 1);
    pfA = fload(R0 - 1);
    pfB = fload(R0);

    #pragma unroll
    for (int k = 0; k < HS + 3; ++k) {
        const int rr = R0 - 1 + k;
        unpk(k & 3, puA);
        puA = puB;
        if (k <= HS) puB = uload(R0 + k + 2);
        __half2 lo = *(reinterpret_cast<__half2*>(&pfA.x));
        __half2 hi = *(reinterpret_cast<__half2*>(&pfA.y));
        float x2v  = __low2float(lo);
        float r20v = __high2float(lo);
        float r21v = __low2float(hi);
        float yv   = __high2float(hi);
        unsigned yraw = pfA.y >> 16;
        pfA = pfB;
        if (k <= HS) pfB = fload(R0 + k + 1);

        compI(rr, (k + 1) & 1, (k + 3) & 3, k & 3, (k + 2) & 3);

        float sN, t0N, t1N;
        compS(rr, (k + 1) & 1, k & 1, yv, x2v, r20v, r21v, yraw,
              (k >= 1 && k <= HS), sN, t0N, t1N);

        {
            float sPrev  = sr[k & 1];
            float t1Prev = t1r[k & 1];
            float hDm1   = (rr < HH) ? 1.f : 0.f;
            v0r[(k + 3) & 3] = mB * (SD(sN) - sN) - t0N;
            v1r[k & 1]       = hDm1 * (sN - sPrev) - t1Prev;
            sr[(k + 1) & 1]  = sN;
            t1r[(k + 1) & 1] = t1N;
        }

        if (k >= 3) compU(R0 - 3 + k, (k + 1) & 3, k & 3, (k + 1) & 1, k & 1,
                          (k + 1) & 3);
    }
}

// ---------------------------------------------------------------------------
// fused01: iterations 0 (analytic) + 1. 58-col cores (lanes 3..60).
// ---------------------------------------------------------------------------
__global__ __launch_bounds__(256) void fused01(
    const float* __restrict__ y, const int* __restrict__ ths_p,
    uint2* __restrict__ f_out, uint2* __restrict__ u_out)
{
    const int tid  = threadIdx.x;
    const int lane = tid & 63;
    const int wid  = swiz_wid(blockIdx.x, tid);
    const int sx   = wid % NSX;
    const int t2   = wid / NSX;
    const int band = t2 & (NBAND - 1);
    const int b    = t2 / NBAND;
    const int R0   = band * HS;
    const int w    = sx * 58 - 3 + lane;
    const int boff = b * (HH * WW);
    const bool wok = ((unsigned)w) < (unsigned)WW;
    const float mA = (w >= 1 && w < WW) ? 1.f : 0.f;
    const float mB = (w >= 0 && w < WW - 1) ? 1.f : 0.f;
    const bool cok = (lane >= 3) && (lane <= 60) && (w < WW);

    const float ths  = (float)ths_p[0];
    const float tl1_ = TAUf * (ths * 0.1f);
    const float l2_  = ths * 0.15f;

    float p0r[4];
    float p1r[2];
    float yD1 = 0.f, yD2 = 0.f, yD3 = 0.f;

    float uf0[4], uf1[4], uf2[4], uf3[4];
    unsigned u12r[4];
    float i0r[2], i1r[2];
    float sr[2], t1r[2];
    float v0r[4], v1r[2];
    #pragma unroll
    for (int q = 0; q < 4; ++q) {
        uf0[q]=uf1[q]=uf2[q]=uf3[q]=0.f; v0r[q]=0.f; u12r[q]=0u; p0r[q]=0.f;
    }
    i0r[0]=i0r[1]=i1r[0]=i1r[1]=0.f;
    sr[0]=sr[1]=0.f; t1r[0]=t1r[1]=0.f; v1r[0]=v1r[1]=0.f; p1r[0]=p1r[1]=0.f;

    auto yload = [&](int row) -> float {
        return (((unsigned)row) < (unsigned)HH && wok)
                   ? y[boff + row * WW + w] : 0.f;
    };
    auto unpk = [&](int slot, uint2 raw) {
        __half2 lo = *(reinterpret_cast<__half2*>(&raw.x));
        __half2 hi = *(reinterpret_cast<__half2*>(&raw.y));
        uf0[slot] = __low2float(lo); uf1[slot] = __high2float(lo);
        uf2[slot] = __low2float(hi); uf3[slot] = __high2float(hi);
        u12r[slot] = (raw.x >> 16) | (raw.y << 16);
    };
    auto compI = [&](int rr, int islot, int c, int d, int uu_) {
        if (((unsigned)rr) < (unsigned)HH) {
            float hD  = (rr < HH - 1) ? 1.f : 0.f;
            unsigned pp = SDu(u12r[c]);
            __half2 ph = *(reinterpret_cast<__half2*>(&pp));
            float u1n = __low2float(ph);
            float u2n = __high2float(ph);
            i0r[islot] = uf0[c] - uf0[d] - u1n + mA * uf1[c];
            i1r[islot] = uf2[c] - u2n - hD * uf3[c] + uf3[uu_];
        } else { i0r[islot] = 0.f; i1r[islot] = 0.f; }
    };

    float pyA = yload(R0 - 4);
    float pyB = yload(R0 - 3);

    #pragma unroll
    for (int j = 0; j < HS + 9; ++j) {
        const int p = R0 - 4 + j;
        float yp = pyA; pyA = pyB;
        if (j <= HS + 6) pyB = yload(R0 - 2 + j);

        p0r[j & 3]       = mB * (SD(yp) - yp);
        p1r[(j + 1) & 1] = ((p < HH) ? 1.f : 0.f) * (yp - yD1);

        if (j >= 3) {
            const int ro = R0 - 6 + j;
            float hD  = (ro < HH - 1) ? 1.f : 0.f;
            float v0c = p0r[(j + 2) & 3], v0u = p0r[(j + 1) & 3];
            float v1c = p1r[j & 1],       v1d = p1r[(j + 1) & 1];
            float G0 = v0c - v0u;
            float G1 = mA * (v0c - SUp(v0c));
            float G2 = v1c - mA * SUp(v1c);
            float G3 = hD * (v1d - v1c);
            float uu0 = SIGMAf * G0, uu1 = SIGMAf * G1;
            float uu2 = SIGMAf * G2, uu3 = SIGMAf * G3;
            float d = uu0*uu0 + uu1*uu1 + uu2*uu2 + uu3*uu3;
            float ui = fminf(l2_ * __builtin_amdgcn_rsqf(d), 1.0f);
            __half2 lo = __floats2half2_rn(RHOf * (uu0 * ui), RHOf * (uu1 * ui));
            __half2 hi = __floats2half2_rn(RHOf * (uu2 * ui), RHOf * (uu3 * ui));
            uint2 st; st.x = *(unsigned*)&lo; st.y = *(unsigned*)&hi;
            unpk((j + 2) & 3, st);
        }

        if (j == 5) compI(R0 - 2, 0, 2, 3, 1);

        if (j >= 6) {
            const int k  = j - 6;
            const int rr = R0 - 1 + k;
            __half yh = __float2half(yD3);
            float yv  = __half2float(yh);
            unsigned yraw = (unsigned)__half_as_ushort(yh);

            compI(rr, (k + 1) & 1, (k + 3) & 3, k & 3, (k + 2) & 3);

            float sN, t0N, t1N;
            {
                const bool coreRow = (k >= 1 && k <= HS);
                if (((unsigned)rr) < (unsigned)HH) {
                    float hD = (rr < HH - 1) ? 1.f : 0.f;
                    float i0c = i0r[(k + 1) & 1], i1c = i1r[(k + 1) & 1];
                    float i1u = i1r[k & 1];
                    float i0l = SUp(i0c);
                    float na = TAUf * (mA * i0l - mB * i0c + i1u - hD * i1c);
                    float x = (yv - na + TAUf * yv) * INV1PT;
                    float rr0 = TAUf * i0c;
                    float rr1 = TAUf * i1c;
                    float d2 = rr0*rr0 + rr1*rr1;
                    float rinv = fminf(tl1_ * __builtin_amdgcn_rsqf(d2), 1.0f);
                    float r0 = rr0 - rr0 * rinv;
                    float r1 = rr1 - rr1 * rinv;
                    sN  = 2.f * x - yv;
                    t0N = 2.f * r0;
                    t1N = 2.f * r1;
                    if (coreRow && cok) {
                        int idx = boff + rr * WW + w;
                        __half2 lo2 = __floats2half2_rn(yv + RHOf * (x - yv),
                                                        RHOf * r0);
                        unsigned r1b = (unsigned)__half_as_ushort(
                            __float2half(RHOf * r1));
                        uint2 st2; st2.x = *(unsigned*)&lo2;
                        st2.y = r1b | (yraw << 16);
                        f_out[(size_t)idx] = st2;
                    }
                } else { sN = 0.f; t0N = 0.f; t1N = 0.f; }
            }

            {
                float sPrev  = sr[k & 1];
                float t1Prev = t1r[k & 1];
                float hDm1   = (rr < HH) ? 1.f : 0.f;
                v0r[(k + 3) & 3] = mB * (SD(sN) - sN) - t0N;
                v1r[k & 1]       = hDm1 * (sN - sPrev) - t1Prev;
                sr[(k + 1) & 1]  = sN;
                t1r[(k + 1) & 1] = t1N;
            }

            if (k >= 3) {
                const int ro = R0 - 3 + k;
                float hD  = (ro < HH - 1) ? 1.f : 0.f;
                float v0c = v0r[(k + 1) & 3], v0u = v0r[k & 3];
                float v1c = v1r[(k + 1) & 1], v1d = v1r[k & 1];
                float v0l = SUp(v0c);
                float v1l = SUp(v1c);
                float G0 = v0c - v0u;
                float G1 = mA * (v0c - v0l);
                float G2 = v1c - mA * v1l;
                float G3 = hD * (v1d - v1c);
                const int us = (k + 1) & 3;
                float u0v = uf0[us], u1v = uf1[us], u2v = uf2[us], u3v = uf3[us];
                float uu0 = u0v + SIGMAf * G0;
                float uu1 = u1v + SIGMAf * G1;
                float uu2 = u2v + SIGMAf * G2;
                float uu3 = u3v + SIGMAf * G3;
                float d = uu0*uu0 + uu1*uu1 + uu2*uu2 + uu3*uu3;
                float ui = fminf(l2_ * __builtin_amdgcn_rsqf(d), 1.0f);
                if (cok) {
                    int idx = boff + ro * WW + w;
                    __half2 lo = __floats2half2_rn(u0v + RHOf * (uu0 * ui - u0v),
                                                   u1v + RHOf * (uu1 * ui - u1v));
                    __half2 hi = __floats2half2_rn(u2v + RHOf * (uu2 * ui - u2v),
                                                   u3v + RHOf * (uu3 * ui - u3v));
                    uint2 st; st.x = *(unsigned*)&lo; st.y = *(unsigned*)&hi;
                    u_out[(size_t)idx] = st;
                }
            }
        }

        yD3 = yD2; yD2 = yD1; yD1 = yp;
    }
}

// ---------------------------------------------------------------------------
// fused89: iter 8 (full mid, producer P) + iter 9 (x-only, consumer C).
// ---------------------------------------------------------------------------
__global__ __launch_bounds__(256) void fused89(
    const int* __restrict__ ths_p,
    const uint2* __restrict__ f_in, const uint2* __restrict__ u_in,
    float* __restrict__ xout)
{
    const int tid  = threadIdx.x;
    const int lane = tid & 63;
    const int wid  = swiz_wid(blockIdx.x, tid);
    const int sx   = wid % NSX;
    const int t2   = wid / NSX;
    const int band = t2 & (NBAND - 1);
    const int b    = t2 / NBAND;
    const int R0   = band * HS;
    const int R0p  = R0 - 2;
    const int w    = sx * 58 - 3 + lane;
    const int boff = b * (HH * WW);
    const bool wok = ((unsigned)w) < (unsigned)WW;
    const float mA = (w >= 1 && w < WW) ? 1.f : 0.f;
    const float mB = (w >= 0 && w < WW - 1) ? 1.f : 0.f;
    const bool cokC = (lane >= 3) && (lane <= 60) && (w < WW);

    const float ths  = (float)ths_p[0];
    const float tl1_ = TAUf * (ths * 0.1f);
    const float l2_  = ths * 0.15f;

    constexpr int HSp = HS + 3;   // 7

    float uf0[4], uf1[4], uf2[4], uf3[4];
    unsigned u12r[4];
    float i0r[2], i1r[2];
    float sr[2], t1r[2];
    float v0r[4], v1r[2];
    float cf0[4], cf1[4], cf2[4], cf3[4];
    unsigned c12[4];
    float ci0[2], ci1[2];
    uint2 fmid[4];
    #pragma unroll
    for (int q = 0; q < 4; ++q) {
        uf0[q]=uf1[q]=uf2[q]=uf3[q]=0.f; v0r[q]=0.f; u12r[q]=0u;
        cf0[q]=cf1[q]=cf2[q]=cf3[q]=0.f; c12[q]=0u;
        fmid[q].x = 0u; fmid[q].y = 0u;
    }
    i0r[0]=i0r[1]=i1r[0]=i1r[1]=0.f;
    ci0[0]=ci0[1]=ci1[0]=ci1[1]=0.f;
    sr[0]=sr[1]=0.f; t1r[0]=t1r[1]=0.f; v1r[0]=v1r[1]=0.f;

    auto uload = [&](int row) -> uint2 {
        uint2 z; z.x = 0u; z.y = 0u;
        if (((unsigned)row) < (unsigned)HH && wok)
            z = u_in[(size_t)(boff + row * WW + w)];
        return z;
    };
    auto fload = [&](int row) -> uint2 {
        uint2 z; z.x = 0u; z.y = 0u;
        if (((unsigned)row) < (unsigned)HH && wok)
            z = f_in[(size_t)(boff + row * WW + w)];
        return z;
    };
    auto unpk = [&](int slot, uint2 raw) {
        __half2 lo = *(reinterpret_cast<__half2*>(&raw.x));
        __half2 hi = *(reinterpret_cast<__half2*>(&raw.y));
        uf0[slot] = __low2float(lo); uf1[slot] = __high2float(lo);
        uf2[slot] = __low2float(hi); uf3[slot] = __high2float(hi);
        u12r[slot] = (raw.x >> 16) | (raw.y << 16);
    };
    auto compI = [&](int rr, int islot, int c, int d, int uu_) {
        if (((unsigned)rr) < (unsigned)HH) {
            float hD  = (rr < HH - 1) ? 1.f : 0.f;
            unsigned pp = SDu(u12r[c]);
            __half2 ph = *(reinterpret_cast<__half2*>(&pp));
            float u1n = __low2float(ph);
            float u2n = __high2float(ph);
            i0r[islot] = uf0[c] - uf0[d] - u1n + mA * uf1[c];
            i1r[islot] = uf2[c] - u2n - hD * uf3[c] + uf3[uu_];
        } else { i0r[islot] = 0.f; i1r[islot] = 0.f; }
    };
    auto cunpk = [&](int slot, uint2 raw) {
        __half2 lo = *(reinterpret_cast<__half2*>(&raw.x));
        __half2 hi = *(reinterpret_cast<__half2*>(&raw.y));
        cf0[slot] = __low2float(lo); cf1[slot] = __high2float(lo);
        cf2[slot] = __low2float(hi); cf3[slot] = __high2float(hi);
        c12[slot] = (raw.x >> 16) | (raw.y << 16);
    };
    auto ccompI = [&](int rr, int islot, int c, int d, int uu_) {
        if (((unsigned)rr) < (unsigned)HH) {
            float hD  = (rr < HH - 1) ? 1.f : 0.f;
            unsigned pp = SDu(c12[c]);
            __half2 ph = *(reinterpret_cast<__half2*>(&pp));
            float u1n = __low2float(ph);
            float u2n = __high2float(ph);
            ci0[islot] = cf0[c] - cf0[d] - u1n + mA * cf1[c];
            ci1[islot] = cf2[c] - u2n - hD * cf3[c] + cf3[uu_];
        } else { ci0[islot] = 0.f; ci1[islot] = 0.f; }
    };

    unpk(1, uload(R0p - 3));
    unpk(2, uload(R0p - 2));
    unpk(3, uload(R0p - 1));
    compI(R0p - 2, 0, 2, 3, 1);
    uint2 puA = uload(R0p);
    uint2 puB = uload(R0p + 1);
    uint2 pfA = fload(R0p - 1);
    uint2 pfB = fload(R0p);

    #pragma unroll
    for (int J = 0; J < HSp + 3; ++J) {       // J = 0..9
        const int rp = R0p - 1 + J;

        unpk(J & 3, puA);
        puA = puB;
        if (J <= HSp) puB = uload(R0p + J + 2);
        __half2 flo = *(reinterpret_cast<__half2*>(&pfA.x));
        __half2 fhi = *(reinterpret_cast<__half2*>(&pfA.y));
        float x2v  = __low2float(flo);
        float r20v = __high2float(flo);
        float r21v = __low2float(fhi);
        float yv   = __high2float(fhi);
        unsigned yraw = pfA.y >> 16;
        pfA = pfB;
        if (J <= HSp) pfB = fload(R0p + J + 1);

        compI(rp, (J + 1) & 1, (J + 3) & 3, J & 3, (J + 2) & 3);

        float sN, t0N, t1N;
        if (((unsigned)rp) < (unsigned)HH) {
            float hD = (rp < HH - 1) ? 1.f : 0.f;
            float i0c = i0r[(J + 1) & 1], i1c = i1r[(J + 1) & 1];
            float i1u = i1r[J & 1];
            float i0l = SUp(i0c);
            float na = TAUf * (mA * i0l - mB * i0c + i1u - hD * i1c);
            float x = (x2v - na + TAUf * yv) * INV1PT;
            float rr0 = r20v + TAUf * i0c;
            float rr1 = r21v + TAUf * i1c;
            float d = rr0 * rr0 + rr1 * rr1;
            float rinv = fminf(tl1_ * __builtin_amdgcn_rsqf(d), 1.0f);
            float r0 = rr0 - rr0 * rinv;
            float r1 = rr1 - rr1 * rinv;
            sN  = 2.f * x  - x2v;
            t0N = 2.f * r0 - r20v;
            t1N = 2.f * r1 - r21v;
            if (J >= 3 && J <= HS + 2) {
                __half2 lo2 = __floats2half2_rn(x2v + RHOf * (x - x2v),
                                                r20v + RHOf * (r0 - r20v));
                unsigned r1b = (unsigned)__half_as_ushort(
                    __float2half(r21v + RHOf * (r1 - r21v)));
                uint2 st; st.x = *(unsigned*)&lo2; st.y = r1b | (yraw << 16);
                fmid[(J + 1) & 3] = st;
            }
        } else { sN = 0.f; t0N = 0.f; t1N = 0.f; }

        {
            float sPrev  = sr[J & 1];
            float t1Prev = t1r[J & 1];
            float hDm1   = (rp < HH) ? 1.f : 0.f;
            v0r[(J + 3) & 3] = mB * (SD(sN) - sN) - t0N;
            v1r[J & 1]       = hDm1 * (sN - sPrev) - t1Prev;
            sr[(J + 1) & 1]  = sN;
            t1r[(J + 1) & 1] = t1N;
        }

        if (J >= 3) {
            const int ro = R0p - 3 + J;
            float hD  = (ro < HH - 1) ? 1.f : 0.f;
            float v0c = v0r[(J + 1) & 3], v0u = v0r[J & 3];
            float v1c = v1r[(J + 1) & 1], v1d = v1r[J & 1];
            float v0l = SUp(v0c);
            float v1l = SUp(v1c);
            float G0 = v0c - v0u;
            float G1 = mA * (v0c - v0l);
            float G2 = v1c - mA * v1l;
            float G3 = hD * (v1d - v1c);
            const int us = (J + 1) & 3;
            float u0v = uf0[us], u1v = uf1[us], u2v = uf2[us], u3v = uf3[us];
            float uu0 = u0v + SIGMAf * G0;
            float uu1 = u1v + SIGMAf * G1;
            float uu2 = u2v + SIGMAf * G2;
            float uu3 = u3v + SIGMAf * G3;
            float d = uu0*uu0 + uu1*uu1 + uu2*uu2 + uu3*uu3;
            float ui = fminf(l2_ * __builtin_amdgcn_rsqf(d), 1.0f);
            uint2 st; st.x = 0u; st.y = 0u;
            if (((unsigned)ro) < (unsigned)HH) {
                __half2 lo = __floats2half2_rn(u0v + RHOf * (uu0 * ui - u0v),
                                               u1v + RHOf * (uu1 * ui - u1v));
                __half2 hi = __floats2half2_rn(u2v + RHOf * (uu2 * ui - u2v),
                                               u3v + RHOf * (uu3 * ui - u3v));
                st.x = *(unsigned*)&lo; st.y = *(unsigned*)&hi;
            }
            cunpk((J + 3) & 3, st);
        }

        if (J == 5) ccompI(R0 - 1, 1, 3, 0, 2);
        if (J >= 6) {
            const int kc = J - 6;
            const int rc = R0 + kc;
            ccompI(rc, kc & 1, kc & 3, (kc + 1) & 3, (kc + 3) & 3);
            uint2 fm = fmid[(J + 2) & 3];
            __half2 mlo = *(reinterpret_cast<__half2*>(&fm.x));
            __half2 mhi = *(reinterpret_cast<__half2*>(&fm.y));
            float cx2 = __low2float(mlo);
            float cyv = __high2float(mhi);
            float hD = (rc < HH - 1) ? 1.f : 0.f;
            float i0c = ci0[kc & 1], i1c = ci1[kc & 1], i1u = ci1[(kc + 1) & 1];
            float i0l = SUp(i0c);
            float na = TAUf * (mA * i0l - mB * i0c + i1u - hD * i1c);
            float x = (cx2 - na + TAUf * cyv) * INV1PT;
            if (cokC) xout[boff + rc * WW + w] = cx2 + RHOf * (x - cx2);
        }
    }
}

extern "C" void kernel_launch(void* const* d_in, const int* in_sizes, int n_in,
                              void* d_out, int out_size, void* d_ws, size_t ws_size,
                              hipStream_t stream)
{
    const float* y   = (const float*)d_in[0];
    const int*   ths = (const int*)d_in[1];
    uint2* ws2 = (uint2*)d_ws;

    uint2* FA = ws2;
    uint2* UA = ws2 + (size_t)NPIX;
    uint2* FB = ws2 + 2 * (size_t)NPIX;
    uint2* UB = ws2 + 3 * (size_t)NPIX;
    float* xout = (float*)d_out;

    dim3 block(256);
    dim3 grid(NBLK);

    // iters 0+1 fused -> A
    fused01<<<grid, block, 0, stream>>>(y, ths, FA, UA);
    // iters 2..7: 6 mid dispatches
    uint2 *fi = FA, *ui = UA, *fo = FB, *uo = UB;
    for (int it = 2; it <= 7; ++it) {
        sweep<1><<<grid, block, 0, stream>>>(y, ths, fi, ui, fo, uo, nullptr);
        uint2* t;
        t = fi; fi = fo; fo = t;
        t = ui; ui = uo; uo = t;
    }
    // iters 8+9 fused -> xout
    fused89<<<grid, block, 0, stream>>>(ths, fi, ui, xout);
}

// Round 18
// 136.968 us; speedup vs baseline: 1.3508x; 1.0005x over previous
//
#include <hip/hip_runtime.h>
#include <hip/hip_fp16.h>
#include <math.h>

#define HH 512
#define WW 512
#define BB 4
#define NPIX (BB * HH * WW)

#define HS 4                 // core rows per wave
#define NSX 9                // fused01/fused89 strips: 9 x 58
#define NBAND (HH / HS)      // 128
#define NWAVES (NSX * NBAND * BB)   // 4608
#define NBLK (NWAVES / 4)           // 1152
#define BPR (NBLK / 8)              // 144

#define NSXP 10              // fusedMM strips: 10 x 56
#define NWAVESP (NSXP * NBAND * BB) // 5120
#define NBLKP (NWAVESP / 4)         // 1280
#define BPRP (NBLKP / 8)            // 160

constexpr float TAUf   = 0.01f;
constexpr float RHOf   = 1.99f;
constexpr float SIGMAf = (float)(1.0 / 0.01 / 72.0);
constexpr float INV1PT = (float)(1.0 / 1.01);

__device__ __forceinline__ float SD(float v) { return __shfl_down(v, 1, 64); }    // lane+1
__device__ __forceinline__ unsigned SDu(unsigned v) { return __shfl_down(v, 1, 64); }
__device__ __forceinline__ float SUp(float v) { return __shfl_up(v, 1, 64); }     // lane-1

// F record (uint2): .x = half2(x2, r0), .y = half2(r1, y_half)
// u record (uint2): .x = half2(u0, u1), .y = half2(u2, u3)

// ---------------------------------------------------------------------------
// fused01: iterations 0 (analytic) + 1. 58-col cores (lanes 3..60).
// ---------------------------------------------------------------------------
__global__ __launch_bounds__(256) void fused01(
    const float* __restrict__ y, const int* __restrict__ ths_p,
    uint2* __restrict__ f_out, uint2* __restrict__ u_out)
{
    const int tid  = threadIdx.x;
    const int lane = tid & 63;
    const int bid  = blockIdx.x;
    const int wid  = (((bid & 7) * BPR) + (bid >> 3)) * 4 + (tid >> 6);
    const int sx   = wid % NSX;
    const int t2   = wid / NSX;
    const int band = t2 & (NBAND - 1);
    const int b    = t2 / NBAND;
    const int R0   = band * HS;
    const int w    = sx * 58 - 3 + lane;
    const int boff = b * (HH * WW);
    const bool wok = ((unsigned)w) < (unsigned)WW;
    const float mA = (w >= 1 && w < WW) ? 1.f : 0.f;
    const float mB = (w >= 0 && w < WW - 1) ? 1.f : 0.f;
    const bool cok = (lane >= 3) && (lane <= 60) && (w < WW);

    const float ths  = (float)ths_p[0];
    const float tl1_ = TAUf * (ths * 0.1f);
    const float l2_  = ths * 0.15f;

    float p0r[4];
    float p1r[2];
    float yD1 = 0.f, yD2 = 0.f, yD3 = 0.f;

    float uf0[4], uf1[4], uf2[4], uf3[4];
    unsigned u12r[4];
    float i0r[2], i1r[2];
    float sr[2], t1r[2];
    float v0r[4], v1r[2];
    #pragma unroll
    for (int q = 0; q < 4; ++q) {
        uf0[q]=uf1[q]=uf2[q]=uf3[q]=0.f; v0r[q]=0.f; u12r[q]=0u; p0r[q]=0.f;
    }
    i0r[0]=i0r[1]=i1r[0]=i1r[1]=0.f;
    sr[0]=sr[1]=0.f; t1r[0]=t1r[1]=0.f; v1r[0]=v1r[1]=0.f; p1r[0]=p1r[1]=0.f;

    auto yload = [&](int row) -> float {
        return (((unsigned)row) < (unsigned)HH && wok)
                   ? y[boff + row * WW + w] : 0.f;
    };
    auto unpk = [&](int slot, uint2 raw) {
        __half2 lo = *(reinterpret_cast<__half2*>(&raw.x));
        __half2 hi = *(reinterpret_cast<__half2*>(&raw.y));
        uf0[slot] = __low2float(lo); uf1[slot] = __high2float(lo);
        uf2[slot] = __low2float(hi); uf3[slot] = __high2float(hi);
        u12r[slot] = (raw.x >> 16) | (raw.y << 16);
    };
    auto compI = [&](int rr, int islot, int c, int d, int uu_) {
        if (((unsigned)rr) < (unsigned)HH) {
            float hD  = (rr < HH - 1) ? 1.f : 0.f;
            unsigned pp = SDu(u12r[c]);
            __half2 ph = *(reinterpret_cast<__half2*>(&pp));
            float u1n = __low2float(ph);
            float u2n = __high2float(ph);
            i0r[islot] = uf0[c] - uf0[d] - u1n + mA * uf1[c];
            i1r[islot] = uf2[c] - u2n - hD * uf3[c] + uf3[uu_];
        } else { i0r[islot] = 0.f; i1r[islot] = 0.f; }
    };

    float pyA = yload(R0 - 4);
    float pyB = yload(R0 - 3);

    #pragma unroll
    for (int j = 0; j < HS + 9; ++j) {
        const int p = R0 - 4 + j;
        float yp = pyA; pyA = pyB;
        if (j <= HS + 6) pyB = yload(R0 - 2 + j);

        p0r[j & 3]       = mB * (SD(yp) - yp);
        p1r[(j + 1) & 1] = ((p < HH) ? 1.f : 0.f) * (yp - yD1);

        if (j >= 3) {
            const int ro = R0 - 6 + j;
            float hD  = (ro < HH - 1) ? 1.f : 0.f;
            float v0c = p0r[(j + 2) & 3], v0u = p0r[(j + 1) & 3];
            float v1c = p1r[j & 1],       v1d = p1r[(j + 1) & 1];
            float G0 = v0c - v0u;
            float G1 = mA * (v0c - SUp(v0c));
            float G2 = v1c - mA * SUp(v1c);
            float G3 = hD * (v1d - v1c);
            float uu0 = SIGMAf * G0, uu1 = SIGMAf * G1;
            float uu2 = SIGMAf * G2, uu3 = SIGMAf * G3;
            float d = uu0*uu0 + uu1*uu1 + uu2*uu2 + uu3*uu3;
            float ui = fminf(l2_ * __builtin_amdgcn_rsqf(d), 1.0f);
            __half2 lo = __floats2half2_rn(RHOf * (uu0 * ui), RHOf * (uu1 * ui));
            __half2 hi = __floats2half2_rn(RHOf * (uu2 * ui), RHOf * (uu3 * ui));
            uint2 st; st.x = *(unsigned*)&lo; st.y = *(unsigned*)&hi;
            unpk((j + 2) & 3, st);
        }

        if (j == 5) compI(R0 - 2, 0, 2, 3, 1);

        if (j >= 6) {
            const int k  = j - 6;
            const int rr = R0 - 1 + k;
            __half yh = __float2half(yD3);
            float yv  = __half2float(yh);
            unsigned yraw = (unsigned)__half_as_ushort(yh);

            compI(rr, (k + 1) & 1, (k + 3) & 3, k & 3, (k + 2) & 3);

            float sN, t0N, t1N;
            {
                const bool coreRow = (k >= 1 && k <= HS);
                if (((unsigned)rr) < (unsigned)HH) {
                    float hD = (rr < HH - 1) ? 1.f : 0.f;
                    float i0c = i0r[(k + 1) & 1], i1c = i1r[(k + 1) & 1];
                    float i1u = i1r[k & 1];
                    float i0l = SUp(i0c);
                    float na = TAUf * (mA * i0l - mB * i0c + i1u - hD * i1c);
                    float x = (yv - na + TAUf * yv) * INV1PT;
                    float rr0 = TAUf * i0c;
                    float rr1 = TAUf * i1c;
                    float d2 = rr0*rr0 + rr1*rr1;
                    float rinv = fminf(tl1_ * __builtin_amdgcn_rsqf(d2), 1.0f);
                    float r0 = rr0 - rr0 * rinv;
                    float r1 = rr1 - rr1 * rinv;
                    sN  = 2.f * x - yv;
                    t0N = 2.f * r0;
                    t1N = 2.f * r1;
                    if (coreRow && cok) {
                        int idx = boff + rr * WW + w;
                        __half2 lo2 = __floats2half2_rn(yv + RHOf * (x - yv),
                                                        RHOf * r0);
                        unsigned r1b = (unsigned)__half_as_ushort(
                            __float2half(RHOf * r1));
                        uint2 st2; st2.x = *(unsigned*)&lo2;
                        st2.y = r1b | (yraw << 16);
                        f_out[(size_t)idx] = st2;
                    }
                } else { sN = 0.f; t0N = 0.f; t1N = 0.f; }
            }

            {
                float sPrev  = sr[k & 1];
                float t1Prev = t1r[k & 1];
                float hDm1   = (rr < HH) ? 1.f : 0.f;
                v0r[(k + 3) & 3] = mB * (SD(sN) - sN) - t0N;
                v1r[k & 1]       = hDm1 * (sN - sPrev) - t1Prev;
                sr[(k + 1) & 1]  = sN;
                t1r[(k + 1) & 1] = t1N;
            }

            if (k >= 3) {
                const int ro = R0 - 3 + k;
                float hD  = (ro < HH - 1) ? 1.f : 0.f;
                float v0c = v0r[(k + 1) & 3], v0u = v0r[k & 3];
                float v1c = v1r[(k + 1) & 1], v1d = v1r[k & 1];
                float v0l = SUp(v0c);
                float v1l = SUp(v1c);
                float G0 = v0c - v0u;
                float G1 = mA * (v0c - v0l);
                float G2 = v1c - mA * v1l;
                float G3 = hD * (v1d - v1c);
                const int us = (k + 1) & 3;
                float u0v = uf0[us], u1v = uf1[us], u2v = uf2[us], u3v = uf3[us];
                float uu0 = u0v + SIGMAf * G0;
                float uu1 = u1v + SIGMAf * G1;
                float uu2 = u2v + SIGMAf * G2;
                float uu3 = u3v + SIGMAf * G3;
                float d = uu0*uu0 + uu1*uu1 + uu2*uu2 + uu3*uu3;
                float ui = fminf(l2_ * __builtin_amdgcn_rsqf(d), 1.0f);
                if (cok) {
                    int idx = boff + ro * WW + w;
                    __half2 lo = __floats2half2_rn(u0v + RHOf * (uu0 * ui - u0v),
                                                   u1v + RHOf * (uu1 * ui - u1v));
                    __half2 hi = __floats2half2_rn(u2v + RHOf * (uu2 * ui - u2v),
                                                   u3v + RHOf * (uu3 * ui - u3v));
                    uint2 st; st.x = *(unsigned*)&lo; st.y = *(unsigned*)&hi;
                    u_out[(size_t)idx] = st;
                }
            }
        }

        yD3 = yD2; yD2 = yD1; yD1 = yp;
    }
}

// ---------------------------------------------------------------------------
// fusedMM: two consecutive mid iterations (state_s -> state_{s+2}).
// Producer P: extended mid pipeline, origin R0P = R0-3, 13 stages (J=0..12),
//   compS rows [R0-4, R0+HS+4], compU rows [R0-3, R0+HS+2] -> pushed to C.
//   F_{s+1} rows [R0-1, R0+HS+1] -> fmid ring (write slot J&3, read lag 3).
// Consumer C: standard mid lagged 6 stages (kc = J-6), stores F/u_{s+2}.
// Lane erosion P±2 then C±2 -> cores lanes [4,59] = 56 cols, NSXP=10 strips.
// ---------------------------------------------------------------------------
__global__ __launch_bounds__(256) void fusedMM(
    const int* __restrict__ ths_p,
    const uint2* __restrict__ f_in, const uint2* __restrict__ u_in,
    uint2* __restrict__ f_out, uint2* __restrict__ u_out)
{
    const int tid  = threadIdx.x;
    const int lane = tid & 63;
    const int bid  = blockIdx.x;
    const int wid  = (((bid & 7) * BPRP) + (bid >> 3)) * 4 + (tid >> 6);
    const int sx   = wid % NSXP;
    const int t2   = wid / NSXP;
    const int band = t2 & (NBAND - 1);
    const int b    = t2 / NBAND;
    const int R0   = band * HS;          // R0 % 4 == 0
    const int w    = sx * 56 - 4 + lane;
    const int boff = b * (HH * WW);
    const bool wok = ((unsigned)w) < (unsigned)WW;
    const float mA = (w >= 1 && w < WW) ? 1.f : 0.f;
    const float mB = (w >= 0 && w < WW - 1) ? 1.f : 0.f;
    const bool cokC = (lane >= 4) && (lane <= 59) && (w < WW);

    const float ths  = (float)ths_p[0];
    const float tl1_ = TAUf * (ths * 0.1f);
    const float l2_  = ths * 0.15f;

    constexpr int HSP = 10;              // P loop: J = 0 .. HSP+2 = 12

    // P rings
    float uf0[4], uf1[4], uf2[4], uf3[4];
    unsigned u12r[4];
    float i0r[2], i1r[2];
    float sr[2], t1r[2];
    float v0r[4], v1r[2];
    // C rings
    float cf0[4], cf1[4], cf2[4], cf3[4];
    unsigned c12[4];
    float ci0[2], ci1[2];
    float csr[2], ct1r[2];
    float cv0[4], cv1[2];
    uint2 fmid[4];
    #pragma unroll
    for (int q = 0; q < 4; ++q) {
        uf0[q]=uf1[q]=uf2[q]=uf3[q]=0.f; v0r[q]=0.f; u12r[q]=0u;
        cf0[q]=cf1[q]=cf2[q]=cf3[q]=0.f; c12[q]=0u; cv0[q]=0.f;
        fmid[q].x = 0u; fmid[q].y = 0u;
    }
    i0r[0]=i0r[1]=i1r[0]=i1r[1]=0.f;
    ci0[0]=ci0[1]=ci1[0]=ci1[1]=0.f;
    sr[0]=sr[1]=0.f; t1r[0]=t1r[1]=0.f; v1r[0]=v1r[1]=0.f;
    csr[0]=csr[1]=0.f; ct1r[0]=ct1r[1]=0.f; cv1[0]=cv1[1]=0.f;

    auto uload = [&](int row) -> uint2 {
        uint2 z; z.x = 0u; z.y = 0u;
        if (((unsigned)row) < (unsigned)HH && wok)
            z = u_in[(size_t)(boff + row * WW + w)];
        return z;
    };
    auto fload = [&](int row) -> uint2 {
        uint2 z; z.x = 0u; z.y = 0u;
        if (((unsigned)row) < (unsigned)HH && wok)
            z = f_in[(size_t)(boff + row * WW + w)];
        return z;
    };
    auto unpk = [&](int slot, uint2 raw) {
        __half2 lo = *(reinterpret_cast<__half2*>(&raw.x));
        __half2 hi = *(reinterpret_cast<__half2*>(&raw.y));
        uf0[slot] = __low2float(lo); uf1[slot] = __high2float(lo);
        uf2[slot] = __low2float(hi); uf3[slot] = __high2float(hi);
        u12r[slot] = (raw.x >> 16) | (raw.y << 16);
    };
    auto compI = [&](int rr, int islot, int c, int d, int uu_) {
        if (((unsigned)rr) < (unsigned)HH) {
            float hD  = (rr < HH - 1) ? 1.f : 0.f;
            unsigned pp = SDu(u12r[c]);
            __half2 ph = *(reinterpret_cast<__half2*>(&pp));
            float u1n = __low2float(ph);
            float u2n = __high2float(ph);
            i0r[islot] = uf0[c] - uf0[d] - u1n + mA * uf1[c];
            i1r[islot] = uf2[c] - u2n - hD * uf3[c] + uf3[uu_];
        } else { i0r[islot] = 0.f; i1r[islot] = 0.f; }
    };
    auto cunpk = [&](int slot, uint2 raw) {
        __half2 lo = *(reinterpret_cast<__half2*>(&raw.x));
        __half2 hi = *(reinterpret_cast<__half2*>(&raw.y));
        cf0[slot] = __low2float(lo); cf1[slot] = __high2float(lo);
        cf2[slot] = __low2float(hi); cf3[slot] = __high2float(hi);
        c12[slot] = (raw.x >> 16) | (raw.y << 16);
    };
    auto ccompI = [&](int rr, int islot, int c, int d, int uu_) {
        if (((unsigned)rr) < (unsigned)HH) {
            float hD  = (rr < HH - 1) ? 1.f : 0.f;
            unsigned pp = SDu(c12[c]);
            __half2 ph = *(reinterpret_cast<__half2*>(&pp));
            float u1n = __low2float(ph);
            float u2n = __high2float(ph);
            ci0[islot] = cf0[c] - cf0[d] - u1n + mA * cf1[c];
            ci1[islot] = cf2[c] - u2n - hD * cf3[c] + cf3[uu_];
        } else { ci0[islot] = 0.f; ci1[islot] = 0.f; }
    };

    // ---- P prologue (origin R0P = R0-3; rows R0-6..R0-4, slots = row&3) ----
    unpk(2, uload(R0 - 6));
    unpk(3, uload(R0 - 5));
    unpk(0, uload(R0 - 4));
    compI(R0 - 5, 1, 3, 0, 2);           // islot=(R0-5)&1=1, c=3, d=0, uu_=2
    uint2 puA = uload(R0 - 3);           // u row consumed at J=0
    uint2 puB = uload(R0 - 2);
    uint2 pfA = fload(R0 - 4);           // F row extracted at J=0
    uint2 pfB = fload(R0 - 3);

    #pragma unroll
    for (int J = 0; J < HSP + 3; ++J) {  // J = 0..12
        const int rp = R0 - 4 + J;       // P compS row

        // ---- P stage ----
        unpk((J + 1) & 3, puA);          // u row R0-3+J, slot (J+1)&3
        puA = puB;
        if (J <= HSP) puB = uload(R0 - 1 + J);
        __half2 flo = *(reinterpret_cast<__half2*>(&pfA.x));
        __half2 fhi = *(reinterpret_cast<__half2*>(&pfA.y));
        float x2v  = __low2float(flo);
        float r20v = __high2float(flo);
        float r21v = __low2float(fhi);
        float yv   = __high2float(fhi);
        unsigned yraw = pfA.y >> 16;
        pfA = pfB;
        if (J <= HSP) pfB = fload(R0 - 2 + J);

        compI(rp, J & 1, J & 3, (J + 1) & 3, (J + 3) & 3);

        float sN, t0N, t1N;
        if (((unsigned)rp) < (unsigned)HH) {
            float hD = (rp < HH - 1) ? 1.f : 0.f;
            float i0c = i0r[J & 1], i1c = i1r[J & 1];
            float i1u = i1r[(J + 1) & 1];
            float i0l = SUp(i0c);
            float na = TAUf * (mA * i0l - mB * i0c + i1u - hD * i1c);
            float x = (x2v - na + TAUf * yv) * INV1PT;
            float rr0 = r20v + TAUf * i0c;
            float rr1 = r21v + TAUf * i1c;
            float d = rr0 * rr0 + rr1 * rr1;
            float rinv = fminf(tl1_ * __builtin_amdgcn_rsqf(d), 1.0f);
            float r0 = rr0 - rr0 * rinv;
            float r1 = rr1 - rr1 * rinv;
            sN  = 2.f * x  - x2v;
            t0N = 2.f * r0 - r20v;
            t1N = 2.f * r1 - r21v;
            if (J >= 3 && J <= 9) {      // F_{s+1} rows [R0-1, R0+HS+1]
                __half2 lo2 = __floats2half2_rn(x2v + RHOf * (x - x2v),
                                                r20v + RHOf * (r0 - r20v));
                unsigned r1b = (unsigned)__half_as_ushort(
                    __float2half(r21v + RHOf * (r1 - r21v)));
                uint2 st; st.x = *(unsigned*)&lo2; st.y = r1b | (yraw << 16);
                fmid[J & 3] = st;        // slot rp&3 = J&3
            }
        } else { sN = 0.f; t0N = 0.f; t1N = 0.f; }

        {
            float sPrev  = sr[(J + 1) & 1];   // s(rp-1)
            float t1Prev = t1r[(J + 1) & 1];
            float hDm1   = (rp < HH) ? 1.f : 0.f;
            v0r[J & 3]       = mB * (SD(sN) - sN) - t0N;       // v0(rp)
            v1r[(J + 1) & 1] = hDm1 * (sN - sPrev) - t1Prev;   // v1(rp-1)
            sr[J & 1]        = sN;
            t1r[J & 1]       = t1N;
        }

        if (J >= 3) {
            // compU(ro = R0-6+J) -> push u_{s+1} to C ring (slot ro&3)
            const int ro = R0 - 6 + J;
            float hD  = (ro < HH - 1) ? 1.f : 0.f;
            float v0c = v0r[(J + 2) & 3], v0u = v0r[(J + 1) & 3];
            float v1c = v1r[J & 1],       v1d = v1r[(J + 1) & 1];
            float v0l = SUp(v0c);
            float v1l = SUp(v1c);
            float G0 = v0c - v0u;
            float G1 = mA * (v0c - v0l);
            float G2 = v1c - mA * v1l;
            float G3 = hD * (v1d - v1c);
            const int us = (J + 2) & 3;       // u_in row ro
            float u0v = uf0[us], u1v = uf1[us], u2v = uf2[us], u3v = uf3[us];
            float uu0 = u0v + SIGMAf * G0;
            float uu1 = u1v + SIGMAf * G1;
            float uu2 = u2v + SIGMAf * G2;
            float uu3 = u3v + SIGMAf * G3;
            float d = uu0*uu0 + uu1*uu1 + uu2*uu2 + uu3*uu3;
            float ui = fminf(l2_ * __builtin_amdgcn_rsqf(d), 1.0f);
            uint2 st; st.x = 0u; st.y = 0u;
            if (((unsigned)ro) < (unsigned)HH) {
                __half2 lo = __floats2half2_rn(u0v + RHOf * (uu0 * ui - u0v),
                                               u1v + RHOf * (uu1 * ui - u1v));
                __half2 hi = __floats2half2_rn(u2v + RHOf * (uu2 * ui - u2v),
                                               u3v + RHOf * (uu3 * ui - u3v));
                st.x = *(unsigned*)&lo; st.y = *(unsigned*)&hi;
            }
            cunpk((J + 2) & 3, st);           // slot ro&3
        }

        // ---- C part (standard mid at origin R0, lag 6) ----
        if (J == 5) ccompI(R0 - 2, 0, 2, 3, 1);
        if (J >= 6) {
            const int kc = J - 6;
            const int rc = R0 - 1 + kc;
            ccompI(rc, (kc + 1) & 1, (kc + 3) & 3, kc & 3, (kc + 2) & 3);

            uint2 fm = fmid[(kc + 3) & 3];    // F_{s+1} row rc (written at J-3)
            __half2 mlo = *(reinterpret_cast<__half2*>(&fm.x));
            __half2 mhi = *(reinterpret_cast<__half2*>(&fm.y));
            float cx2  = __low2float(mlo);
            float cr0  = __high2float(mlo);
            float cr1  = __low2float(mhi);
            float cyv  = __high2float(mhi);
            unsigned cyraw = fm.y >> 16;

            float csN, ct0N, ct1N;
            if (((unsigned)rc) < (unsigned)HH) {
                float hD = (rc < HH - 1) ? 1.f : 0.f;
                float i0c = ci0[(kc + 1) & 1], i1c = ci1[(kc + 1) & 1];
                float i1u = ci1[kc & 1];
                float i0l = SUp(i0c);
                float na = TAUf * (mA * i0l - mB * i0c + i1u - hD * i1c);
                float x = (cx2 - na + TAUf * cyv) * INV1PT;
                float rr0 = cr0 + TAUf * i0c;
                float rr1 = cr1 + TAUf * i1c;
                float d = rr0 * rr0 + rr1 * rr1;
                float rinv = fminf(tl1_ * __builtin_amdgcn_rsqf(d), 1.0f);
                float r0 = rr0 - rr0 * rinv;
                float r1 = rr1 - rr1 * rinv;
                csN  = 2.f * x  - cx2;
                ct0N = 2.f * r0 - cr0;
                ct1N = 2.f * r1 - cr1;
                if (kc >= 1 && kc <= HS && cokC) {
                    int idx = boff + rc * WW + w;
                    __half2 lo2 = __floats2half2_rn(cx2 + RHOf * (x - cx2),
                                                    cr0 + RHOf * (r0 - cr0));
                    unsigned r1b = (unsigned)__half_as_ushort(
                        __float2half(cr1 + RHOf * (r1 - cr1)));
                    uint2 st; st.x = *(unsigned*)&lo2; st.y = r1b | (cyraw << 16);
                    f_out[(size_t)idx] = st;
                }
            } else { csN = 0.f; ct0N = 0.f; ct1N = 0.f; }

            {
                float sPrev  = csr[kc & 1];
                float t1Prev = ct1r[kc & 1];
                float hDm1   = (rc < HH) ? 1.f : 0.f;
                cv0[(kc + 3) & 3] = mB * (SD(csN) - csN) - ct0N;
                cv1[kc & 1]       = hDm1 * (csN - sPrev) - t1Prev;
                csr[(kc + 1) & 1] = csN;
                ct1r[(kc + 1) & 1]= ct1N;
            }

            if (kc >= 3) {
                const int ro = R0 - 3 + kc;       // core rows R0..R0+HS-1
                float hD  = (ro < HH - 1) ? 1.f : 0.f;
                float v0c = cv0[(kc + 1) & 3], v0u = cv0[kc & 3];
                float v1c = cv1[(kc + 1) & 1], v1d = cv1[kc & 1];
                float v0l = SUp(v0c);
                float v1l = SUp(v1c);
                float G0 = v0c - v0u;
                float G1 = mA * (v0c - v0l);
                float G2 = v1c - mA * v1l;
                float G3 = hD * (v1d - v1c);
                const int us = (kc + 1) & 3;      // u_{s+1} row ro
                float u0v = cf0[us], u1v = cf1[us], u2v = cf2[us], u3v = cf3[us];
                float uu0 = u0v + SIGMAf * G0;
                float uu1 = u1v + SIGMAf * G1;
                float uu2 = u2v + SIGMAf * G2;
                float uu3 = u3v + SIGMAf * G3;
                float d = uu0*uu0 + uu1*uu1 + uu2*uu2 + uu3*uu3;
                float ui = fminf(l2_ * __builtin_amdgcn_rsqf(d), 1.0f);
                if (cokC) {
                    int idx = boff + ro * WW + w;
                    __half2 lo = __floats2half2_rn(u0v + RHOf * (uu0 * ui - u0v),
                                                   u1v + RHOf * (uu1 * ui - u1v));
                    __half2 hi = __floats2half2_rn(u2v + RHOf * (uu2 * ui - u2v),
                                                   u3v + RHOf * (uu3 * ui - u3v));
                    uint2 st; st.x = *(unsigned*)&lo; st.y = *(unsigned*)&hi;
                    u_out[(size_t)idx] = st;
                }
            }
        }
    }
}

// ---------------------------------------------------------------------------
// fused89: iter 8 (full mid, producer P) + iter 9 (x-only, consumer C).
// ---------------------------------------------------------------------------
__global__ __launch_bounds__(256) void fused89(
    const int* __restrict__ ths_p,
    const uint2* __restrict__ f_in, const uint2* __restrict__ u_in,
    float* __restrict__ xout)
{
    const int tid  = threadIdx.x;
    const int lane = tid & 63;
    const int bid  = blockIdx.x;
    const int wid  = (((bid & 7) * BPR) + (bid >> 3)) * 4 + (tid >> 6);
    const int sx   = wid % NSX;
    const int t2   = wid / NSX;
    const int band = t2 & (NBAND - 1);
    const int b    = t2 / NBAND;
    const int R0   = band * HS;
    const int R0p  = R0 - 2;
    const int w    = sx * 58 - 3 + lane;
    const int boff = b * (HH * WW);
    const bool wok = ((unsigned)w) < (unsigned)WW;
    const float mA = (w >= 1 && w < WW) ? 1.f : 0.f;
    const float mB = (w >= 0 && w < WW - 1) ? 1.f : 0.f;
    const bool cokC = (lane >= 3) && (lane <= 60) && (w < WW);

    const float ths  = (float)ths_p[0];
    const float tl1_ = TAUf * (ths * 0.1f);
    const float l2_  = ths * 0.15f;

    constexpr int HSp = HS + 3;   // 7

    float uf0[4], uf1[4], uf2[4], uf3[4];
    unsigned u12r[4];
    float i0r[2], i1r[2];
    float sr[2], t1r[2];
    float v0r[4], v1r[2];
    float cf0[4], cf1[4], cf2[4], cf3[4];
    unsigned c12[4];
    float ci0[2], ci1[2];
    uint2 fmid[4];
    #pragma unroll
    for (int q = 0; q < 4; ++q) {
        uf0[q]=uf1[q]=uf2[q]=uf3[q]=0.f; v0r[q]=0.f; u12r[q]=0u;
        cf0[q]=cf1[q]=cf2[q]=cf3[q]=0.f; c12[q]=0u;
        fmid[q].x = 0u; fmid[q].y = 0u;
    }
    i0r[0]=i0r[1]=i1r[0]=i1r[1]=0.f;
    ci0[0]=ci0[1]=ci1[0]=ci1[1]=0.f;
    sr[0]=sr[1]=0.f; t1r[0]=t1r[1]=0.f; v1r[0]=v1r[1]=0.f;

    auto uload = [&](int row) -> uint2 {
        uint2 z; z.x = 0u; z.y = 0u;
        if (((unsigned)row) < (unsigned)HH && wok)
            z = u_in[(size_t)(boff + row * WW + w)];
        return z;
    };
    auto fload = [&](int row) -> uint2 {
        uint2 z; z.x = 0u; z.y = 0u;
        if (((unsigned)row) < (unsigned)HH && wok)
            z = f_in[(size_t)(boff + row * WW + w)];
        return z;
    };
    auto unpk = [&](int slot, uint2 raw) {
        __half2 lo = *(reinterpret_cast<__half2*>(&raw.x));
        __half2 hi = *(reinterpret_cast<__half2*>(&raw.y));
        uf0[slot] = __low2float(lo); uf1[slot] = __high2float(lo);
        uf2[slot] = __low2float(hi); uf3[slot] = __high2float(hi);
        u12r[slot] = (raw.x >> 16) | (raw.y << 16);
    };
    auto compI = [&](int rr, int islot, int c, int d, int uu_) {
        if (((unsigned)rr) < (unsigned)HH) {
            float hD  = (rr < HH - 1) ? 1.f : 0.f;
            unsigned pp = SDu(u12r[c]);
            __half2 ph = *(reinterpret_cast<__half2*>(&pp));
            float u1n = __low2float(ph);
            float u2n = __high2float(ph);
            i0r[islot] = uf0[c] - uf0[d] - u1n + mA * uf1[c];
            i1r[islot] = uf2[c] - u2n - hD * uf3[c] + uf3[uu_];
        } else { i0r[islot] = 0.f; i1r[islot] = 0.f; }
    };
    auto cunpk = [&](int slot, uint2 raw) {
        __half2 lo = *(reinterpret_cast<__half2*>(&raw.x));
        __half2 hi = *(reinterpret_cast<__half2*>(&raw.y));
        cf0[slot] = __low2float(lo); cf1[slot] = __high2float(lo);
        cf2[slot] = __low2float(hi); cf3[slot] = __high2float(hi);
        c12[slot] = (raw.x >> 16) | (raw.y << 16);
    };
    auto ccompI = [&](int rr, int islot, int c, int d, int uu_) {
        if (((unsigned)rr) < (unsigned)HH) {
            float hD  = (rr < HH - 1) ? 1.f : 0.f;
            unsigned pp = SDu(c12[c]);
            __half2 ph = *(reinterpret_cast<__half2*>(&pp));
            float u1n = __low2float(ph);
            float u2n = __high2float(ph);
            ci0[islot] = cf0[c] - cf0[d] - u1n + mA * cf1[c];
            ci1[islot] = cf2[c] - u2n - hD * cf3[c] + cf3[uu_];
        } else { ci0[islot] = 0.f; ci1[islot] = 0.f; }
    };

    unpk(1, uload(R0p - 3));
    unpk(2, uload(R0p - 2));
    unpk(3, uload(R0p - 1));
    compI(R0p - 2, 0, 2, 3, 1);
    uint2 puA = uload(R0p);
    uint2 puB = uload(R0p + 1);
    uint2 pfA = fload(R0p - 1);
    uint2 pfB = fload(R0p);

    #pragma unroll
    for (int J = 0; J < HSp + 3; ++J) {       // J = 0..9
        const int rp = R0p - 1 + J;

        unpk(J & 3, puA);
        puA = puB;
        if (J <= HSp) puB = uload(R0p + J + 2);
        __half2 flo = *(reinterpret_cast<__half2*>(&pfA.x));
        __half2 fhi = *(reinterpret_cast<__half2*>(&pfA.y));
        float x2v  = __low2float(flo);
        float r20v = __high2float(flo);
        float r21v = __low2float(fhi);
        float yv   = __high2float(fhi);
        unsigned yraw = pfA.y >> 16;
        pfA = pfB;
        if (J <= HSp) pfB = fload(R0p + J + 1);

        compI(rp, (J + 1) & 1, (J + 3) & 3, J & 3, (J + 2) & 3);

        float sN, t0N, t1N;
        if (((unsigned)rp) < (unsigned)HH) {
            float hD = (rp < HH - 1) ? 1.f : 0.f;
            float i0c = i0r[(J + 1) & 1], i1c = i1r[(J + 1) & 1];
            float i1u = i1r[J & 1];
            float i0l = SUp(i0c);
            float na = TAUf * (mA * i0l - mB * i0c + i1u - hD * i1c);
            float x = (x2v - na + TAUf * yv) * INV1PT;
            float rr0 = r20v + TAUf * i0c;
            float rr1 = r21v + TAUf * i1c;
            float d = rr0 * rr0 + rr1 * rr1;
            float rinv = fminf(tl1_ * __builtin_amdgcn_rsqf(d), 1.0f);
            float r0 = rr0 - rr0 * rinv;
            float r1 = rr1 - rr1 * rinv;
            sN  = 2.f * x  - x2v;
            t0N = 2.f * r0 - r20v;
            t1N = 2.f * r1 - r21v;
            if (J >= 3 && J <= HS + 2) {
                __half2 lo2 = __floats2half2_rn(x2v + RHOf * (x - x2v),
                                                r20v + RHOf * (r0 - r20v));
                unsigned r1b = (unsigned)__half_as_ushort(
                    __float2half(r21v + RHOf * (r1 - r21v)));
                uint2 st; st.x = *(unsigned*)&lo2; st.y = r1b | (yraw << 16);
                fmid[(J + 1) & 3] = st;
            }
        } else { sN = 0.f; t0N = 0.f; t1N = 0.f; }

        {
            float sPrev  = sr[J & 1];
            float t1Prev = t1r[J & 1];
            float hDm1   = (rp < HH) ? 1.f : 0.f;
            v0r[(J + 3) & 3] = mB * (SD(sN) - sN) - t0N;
            v1r[J & 1]       = hDm1 * (sN - sPrev) - t1Prev;
            sr[(J + 1) & 1]  = sN;
            t1r[(J + 1) & 1] = t1N;
        }

        if (J >= 3) {
            const int ro = R0p - 3 + J;
            float hD  = (ro < HH - 1) ? 1.f : 0.f;
            float v0c = v0r[(J + 1) & 3], v0u = v0r[J & 3];
            float v1c = v1r[(J + 1) & 1], v1d = v1r[J & 1];
            float v0l = SUp(v0c);
            float v1l = SUp(v1c);
            float G0 = v0c - v0u;
            float G1 = mA * (v0c - v0l);
            float G2 = v1c - mA * v1l;
            float G3 = hD * (v1d - v1c);
            const int us = (J + 1) & 3;
            float u0v = uf0[us], u1v = uf1[us], u2v = uf2[us], u3v = uf3[us];
            float uu0 = u0v + SIGMAf * G0;
            float uu1 = u1v + SIGMAf * G1;
            float uu2 = u2v + SIGMAf * G2;
            float uu3 = u3v + SIGMAf * G3;
            float d = uu0*uu0 + uu1*uu1 + uu2*uu2 + uu3*uu3;
            float ui = fminf(l2_ * __builtin_amdgcn_rsqf(d), 1.0f);
            uint2 st; st.x = 0u; st.y = 0u;
            if (((unsigned)ro) < (unsigned)HH) {
                __half2 lo = __floats2half2_rn(u0v + RHOf * (uu0 * ui - u0v),
                                               u1v + RHOf * (uu1 * ui - u1v));
                __half2 hi = __floats2half2_rn(u2v + RHOf * (uu2 * ui - u2v),
                                               u3v + RHOf * (uu3 * ui - u3v));
                st.x = *(unsigned*)&lo; st.y = *(unsigned*)&hi;
            }
            cunpk((J + 3) & 3, st);
        }

        if (J == 5) ccompI(R0 - 1, 1, 3, 0, 2);
        if (J >= 6) {
            const int kc = J - 6;
            const int rc = R0 + kc;
            ccompI(rc, kc & 1, kc & 3, (kc + 1) & 3, (kc + 3) & 3);
            uint2 fm = fmid[(J + 2) & 3];
            __half2 mlo = *(reinterpret_cast<__half2*>(&fm.x));
            __half2 mhi = *(reinterpret_cast<__half2*>(&fm.y));
            float cx2 = __low2float(mlo);
            float cyv = __high2float(mhi);
            float hD = (rc < HH - 1) ? 1.f : 0.f;
            float i0c = ci0[kc & 1], i1c = ci1[kc & 1], i1u = ci1[(kc + 1) & 1];
            float i0l = SUp(i0c);
            float na = TAUf * (mA * i0l - mB * i0c + i1u - hD * i1c);
            float x = (cx2 - na + TAUf * cyv) * INV1PT;
            if (cokC) xout[boff + rc * WW + w] = cx2 + RHOf * (x - cx2);
        }
    }
}

extern "C" void kernel_launch(void* const* d_in, const int* in_sizes, int n_in,
                              void* d_out, int out_size, void* d_ws, size_t ws_size,
                              hipStream_t stream)
{
    const float* y   = (const float*)d_in[0];
    const int*   ths = (const int*)d_in[1];
    uint2* ws2 = (uint2*)d_ws;

    uint2* FA = ws2;
    uint2* UA = ws2 + (size_t)NPIX;
    uint2* FB = ws2 + 2 * (size_t)NPIX;
    uint2* UB = ws2 + 3 * (size_t)NPIX;
    float* xout = (float*)d_out;

    dim3 block(256);

    // iters 0+1 fused -> state1 in A
    fused01<<<dim3(NBLK), block, 0, stream>>>(y, ths, FA, UA);
    // iters 2+3 -> state3 in B; 4+5 -> state5 in A; 6+7 -> state7 in B
    fusedMM<<<dim3(NBLKP), block, 0, stream>>>(ths, FA, UA, FB, UB);
    fusedMM<<<dim3(NBLKP), block, 0, stream>>>(ths, FB, UB, FA, UA);
    fusedMM<<<dim3(NBLKP), block, 0, stream>>>(ths, FA, UA, FB, UB);
    // iters 8+9 fused -> xout
    fused89<<<dim3(NBLK), block, 0, stream>>>(ths, FB, UB, xout);
}